// Round 8
// baseline (238.690 us; speedup 1.0000x reference)
//
#include <hip/hip_runtime.h>
#include <math.h>

// N=4, C=256, H=W=32, NH=2, HD=128, MAX_DIS=7, WS=15, WW=225, T=sqrt(128)
// out: [hw=1024][n=4][c=256] fp32

__device__ __forceinline__ int iclamp(int v, int lo, int hi) {
    return v < lo ? lo : (v > hi ? hi : v);
}

// ---------------------------------------------------------------------------
// Tiled fp32 GEMM body: Y(64x64 tile) = W[M,K] x X[K,1024], BK=32.
// flags: 2 = interleaved store (Y[(col)*ldI + storeOff + row]), 4 = atomicAdd,
//        8 = padded-V store (Y[gd*1536 + row*48 + col + 8], row=m>>5,col=m&31)
// K multiple of 32. X has 1024 columns.
// ---------------------------------------------------------------------------
__device__ __forceinline__
void gemm_body(const float* __restrict__ Wb, const float* __restrict__ Xb,
               const float* __restrict__ biasb, float* __restrict__ Yb,
               int M, int K, int kt0, int kt1, bool addBias, int flags,
               long storeOff, int ldI)
{
    __shared__ __align__(16) float sm[64 * 68];   // 17.4 KB
    float* Ws = sm;               // [32][68] k-major, d contiguous
    float* Xs = sm + 32 * 68;     // [32][64] k-major, m contiguous

    const int row0 = blockIdx.y * 64;
    const int col0 = blockIdx.x * 64;
    const int tid = threadIdx.x;
    const int tx = tid & 15, ty = tid >> 4;

    float acc[4][4];
#pragma unroll
    for (int i = 0; i < 4; ++i)
#pragma unroll
        for (int j = 0; j < 4; ++j) acc[i][j] = 0.f;

    for (int kt = kt0; kt < kt1; ++kt) {
        const int c0 = kt * 32;
#pragma unroll
        for (int i = 0; i < 2; ++i) {
            int e = tid + i * 256;
            int dd = e >> 3, c4 = (e & 7) * 4;
            int gd = row0 + dd;
            float4 w4 = make_float4(0.f, 0.f, 0.f, 0.f);
            if (gd < M) w4 = *(const float4*)&Wb[(long)gd * K + c0 + c4];
            Ws[(c4 + 0) * 68 + dd] = w4.x;
            Ws[(c4 + 1) * 68 + dd] = w4.y;
            Ws[(c4 + 2) * 68 + dd] = w4.z;
            Ws[(c4 + 3) * 68 + dd] = w4.w;
        }
#pragma unroll
        for (int i = 0; i < 2; ++i) {
            int e = tid + i * 256;
            int cc = e >> 4, m4 = (e & 15) * 4;
            float4 x4 = *(const float4*)&Xb[((long)(c0 + cc) << 10) + col0 + m4];
            *(float4*)&Xs[cc * 64 + m4] = x4;
        }
        __syncthreads();
#pragma unroll
        for (int k = 0; k < 32; ++k) {
            const float4 a4 = *(const float4*)&Ws[k * 68 + ty * 4];
            const float4 b4 = *(const float4*)&Xs[k * 64 + tx * 4];
            float av[4] = {a4.x, a4.y, a4.z, a4.w};
            float bv[4] = {b4.x, b4.y, b4.z, b4.w};
#pragma unroll
            for (int i = 0; i < 4; ++i)
#pragma unroll
                for (int j = 0; j < 4; ++j) acc[i][j] += av[i] * bv[j];
        }
        __syncthreads();
    }

    if (flags & 8) {
        int m4 = col0 + tx * 4;
        int row = m4 >> 5, col = (m4 & 31) + 8;
#pragma unroll
        for (int i = 0; i < 4; ++i) {
            int gd = row0 + ty * 4 + i;
            float bvv = (addBias && biasb) ? biasb[gd] : 0.f;
            long off = (long)gd * 1536 + row * 48 + col;
            Yb[off + 0] = acc[i][0] + bvv;
            Yb[off + 1] = acc[i][1] + bvv;
            Yb[off + 2] = acc[i][2] + bvv;
            Yb[off + 3] = acc[i][3] + bvv;
        }
    } else if (!(flags & 2)) {
#pragma unroll
        for (int i = 0; i < 4; ++i) {
            int gd = row0 + ty * 4 + i;
            if (gd >= M) continue;
            float bvv = (addBias && biasb) ? biasb[gd] : 0.f;
            long yoff = ((long)gd << 10) + col0 + tx * 4;
            if (flags & 4) {
#pragma unroll
                for (int j = 0; j < 4; ++j)
                    atomicAdd(&Yb[yoff + j], acc[i][j] + bvv);
            } else {
                float4 r;
                r.x = acc[i][0] + bvv; r.y = acc[i][1] + bvv;
                r.z = acc[i][2] + bvv; r.w = acc[i][3] + bvv;
                *(float4*)&Yb[yoff] = r;
            }
        }
    } else {
        float* tile = sm;  // [64 m][68 d]
#pragma unroll
        for (int i = 0; i < 4; ++i) {
            float bvv = (addBias && biasb) ? biasb[row0 + ty * 4 + i] : 0.f;
#pragma unroll
            for (int j = 0; j < 4; ++j)
                tile[(tx * 4 + j) * 68 + ty * 4 + i] = acc[i][j] + bvv;
        }
        __syncthreads();
#pragma unroll
        for (int it = 0; it < 16; ++it) {
            int e = tid + it * 256;
            int dd = e & 63, mm = e >> 6;
            long off = (long)(col0 + mm) * ldI + storeOff + row0 + dd;
            if (flags & 4) atomicAdd(&Yb[off], tile[mm * 68 + dd]);
            else Yb[off] = tile[mm * 68 + dd];
        }
    }
}

__global__ __launch_bounds__(256)
void gemm_kernel(const float* __restrict__ W, const float* __restrict__ X,
                 const float* __restrict__ bias, float* __restrict__ Y,
                 int M, int K, long wStride, int wMod,
                 long xStride, long yStride, int biasStride, int biasMod,
                 int flags, int kSplit, int ldI)
{
    int b = blockIdx.z / kSplit;
    int ks = blockIdx.z - b * kSplit;
    int ktiles = (K + 31) >> 5;
    int kt0 = ks * ktiles / kSplit, kt1 = (ks + 1) * ktiles / kSplit;
    const float* Wb = W + (long)(b % wMod) * wStride;
    const float* Xb = X + (long)b * xStride;
    const float* biasb = bias ? (bias + (long)(b % biasMod) * biasStride) : nullptr;
    float* Yb; long storeOff = 0;
    if (flags & 2) { Yb = Y; storeOff = (long)b * M; }
    else           { Yb = Y + (long)b * yStride; }
    gemm_body(Wb, Xb, biasb, Yb, M, K, kt0, kt1, ks == 0, flags, storeOff, ldI);
}

// Q,K,V projections fused: blockIdx.z = sel*4 + batch. V goes to padded layout.
__global__ __launch_bounds__(256)
void qkv_kernel(const float* __restrict__ q, const float* __restrict__ k,
                const float* __restrict__ v,
                const float* __restrict__ Wq, const float* __restrict__ Wk,
                const float* __restrict__ Wv,
                const float* __restrict__ bq, const float* __restrict__ bk,
                const float* __restrict__ bv,
                float* __restrict__ qp, float* __restrict__ kp,
                float* __restrict__ vpad)
{
    int b = blockIdx.z;
    int sel = b >> 2, batch = b & 3;
    if (sel == 2) {
        gemm_body(Wv, v + ((long)batch << 18), bv, vpad + (long)batch * 393216,
                  256, 256, 0, 8, true, 8, 0, 0);
    } else {
        const float *W, *X, *bias; float* Y;
        if (sel == 0) { W = Wq; X = q; bias = bq; Y = qp; }
        else          { W = Wk; X = k; bias = bk; Y = kp; }
        gemm_body(W, X + ((long)batch << 18), bias, Y + ((long)batch << 18),
                  256, 256, 0, 8, true, 0, 0, 0);
    }
}

// ---------------------------------------------------------------------------
// scores v3 + softmax: block = (y, x-octet, ng). grid (128,8) = 1024 blocks,
// 8 px/block, ~11.9 KB LDS -> 4 blocks/CU, 4 waves/SIMD.
// thread = (dy 16, xp 2, cq 8): 16 channels, acc[4 px][15 dx], 20-float
// aligned K register window (5 float4). cq sits in lane bits [2:0]; the
// 128-ch sum is combined with 3 shfl_xor (butterfly), then 8 static branches
// distribute masked raw-score writes to LDS. rel added coalescedly after.
// ---------------------------------------------------------------------------
__global__ __launch_bounds__(256)
void scores_kernel(const float* __restrict__ qp, const float* __restrict__ kp,
                   float* __restrict__ relattn)
{
    __shared__ __align__(16) float qs[128 * 8];    // [c][8 px], scaled by 1/T
    __shared__ float qk[8 * 241];                  // [px][15*16 + pad]
    __shared__ float invl[8];

    const int tid = threadIdx.x;
    const int y  = blockIdx.x >> 2;           // 0..31
    const int xo = blockIdx.x & 3;            // x-octet
    const int bz = blockIdx.y;                // n*2+g
    const long hoff = (long)((bz >> 1) * 256 + (bz & 1) * 128) << 10;
    const float* qh = qp + hoff;
    const float* kh = kp + hoff;
    float* relh = relattn + (long)bz * 230400;
    const float invT = 0.08838834764831845f;  // 1/sqrt(128)
    const int xbase = xo * 8;

    // stage q: [128 c][8 px]
    for (int e = tid; e < 1024; e += 256) {
        int c = e >> 3, x = e & 7;
        qs[e] = qh[((long)c << 10) + y * 32 + xbase + x] * invT;
    }
    __syncthreads();

    const int dy = tid >> 4;          // 0..15 (15 inactive)
    const int xp = (tid >> 3) & 1;    // px quad
    const int cq = tid & 7;           // channel group (16 ch), lane bits [2:0]
    const int x0l = xp * 4;
    const int x0g = xbase + x0l;
    const bool active = (dy < 15);
    const int ky = y + dy - 7;        // unclamped read, memory-safe inside ws

    float acc[4][15];
#pragma unroll
    for (int i = 0; i < 4; ++i)
#pragma unroll
        for (int dx = 0; dx < 15; ++dx) acc[i][dx] = 0.f;

    if (active) {
        const float* kr = kh + (long)ky * 32 + (x0g - 8);   // 16B-aligned
        const int cbase = cq * 16;
#pragma unroll 2
        for (int cc = 0; cc < 16; ++cc) {
            const int c = cbase + cc;
            const float4* p4 = (const float4*)(kr + ((long)c << 10));
            float4 w0 = p4[0], w1 = p4[1], w2 = p4[2], w3 = p4[3], w4 = p4[4];
            float w[20] = {w0.x, w0.y, w0.z, w0.w, w1.x, w1.y, w1.z, w1.w,
                           w2.x, w2.y, w2.z, w2.w, w3.x, w3.y, w3.z, w3.w,
                           w4.x, w4.y, w4.z, w4.w};
            const float4 q4 = *(const float4*)&qs[c * 8 + x0l];
            float qa[4] = {q4.x, q4.y, q4.z, q4.w};
#pragma unroll
            for (int i = 0; i < 4; ++i)
#pragma unroll
                for (int dx = 0; dx < 15; ++dx)
                    acc[i][dx] += qa[i] * w[i + dx + 1];
        }
    }

    // butterfly over the 8 cq lanes: every lane ends with the 128-ch sum
#pragma unroll
    for (int i = 0; i < 4; ++i)
#pragma unroll
        for (int dx = 0; dx < 15; ++dx) {
            float v = acc[i][dx];
            v += __shfl_xor(v, 1);
            v += __shfl_xor(v, 2);
            v += __shfl_xor(v, 4);
            acc[i][dx] = v;
        }

    // distribute masked raw-score writes: lane cq = dxh*4 + i
    const bool vy = (ky >= 0) && (ky < 32);
    if (active) {
#pragma unroll
        for (int j = 0; j < 8; ++j) {
            if (cq == j) {
                const int i = j & 3;          // px within quad (static)
                const int dxh = j >> 2;       // dx half (static)
                const int px = x0l + i;
                const int dx0 = dxh * 8;
                const int ndx = dxh ? 7 : 8;
#pragma unroll
                for (int d = 0; d < ndx; ++d) {
                    int dx = dx0 + d;
                    int hx = x0g + i + dx - 7;
                    float val = (vy && hx >= 0 && hx < 32) ? acc[i][dx] : -1e8f;
                    qk[px * 241 + dy * 16 + dx] = val;
                }
                if (dxh) qk[px * 241 + dy * 16 + 15] = -1e8f;   // pad slot
            }
        }
    }
    __syncthreads();

    // rel-add pass, coalesced by w (invalid slots stay ~ -1e8)
    for (int e = tid; e < 1800; e += 256) {
        int px = e & 7, w = e >> 3;
        int dy2 = w / 15, dx2 = w - dy2 * 15;
        qk[px * 241 + dy2 * 16 + dx2] += relh[((long)w << 10) + y * 32 + xbase + px];
    }
    __syncthreads();

    // softmax over 240 slots: 32 threads per px
    {
        int px = tid >> 5, s = tid & 31;
        float mx = -3.0e38f;
        for (int w = s; w < 240; w += 32) mx = fmaxf(mx, qk[px * 241 + w]);
#pragma unroll
        for (int msk = 16; msk; msk >>= 1) mx = fmaxf(mx, __shfl_xor(mx, msk));
        float sum = 0.f;
        for (int w = s; w < 240; w += 32) {
            float p = __expf(qk[px * 241 + w] - mx);
            qk[px * 241 + w] = p;
            sum += p;
        }
#pragma unroll
        for (int msk = 16; msk; msk >>= 1) sum += __shfl_xor(sum, msk);
        if (s == 0) invl[px] = 1.0f / sum;
    }
    __syncthreads();

    // write normalized attention back, coalesced by w
    for (int e = tid; e < 1800; e += 256) {
        int px = e & 7, w = e >> 3;
        int dy2 = w / 15, dx2 = w - dy2 * 15;
        relh[((long)w << 10) + y * 32 + xbase + px] =
            qk[px * 241 + dy2 * 16 + dx2] * invl[px];
    }
}

// ---------------------------------------------------------------------------
// PV v4: padded V, register window, dy-half split. (unchanged)
// ---------------------------------------------------------------------------
__global__ __launch_bounds__(256)
void pv_kernel(const float* __restrict__ vpad, const float* __restrict__ attn,
               const float* __restrict__ Vbias, float* __restrict__ agg)
{
    __shared__ __align__(16) float pa[120 * 32];   // 15.36 KB
    const int tid = threadIdx.x;
    const int y   = blockIdx.x;          // 0..31
    const int chh = blockIdx.y & 1;      // channel half
    const int dyh = blockIdx.y >> 1;     // dy half
    const int bz  = blockIdx.z;          // n*2+g
    const int n = bz >> 1, g = bz & 1;

    const int dy0 = dyh * 8;
    const int ndy = dyh ? 7 : 8;
    const int w0  = dy0 * 15;
    const int nw  = ndy * 15;

    const float* ab = attn + (long)bz * 230400 + ((long)w0 << 10) + y * 32;
    for (int e = tid; e < nw * 8; e += 256) {
        int w = e >> 3, x4 = (e & 7) * 4;
        *(float4*)&pa[w * 32 + x4] = *(const float4*)&ab[((long)w << 10) + x4];
    }
    __syncthreads();

    const int chg = tid >> 3;            // 0..31 -> 2 channels each
    const int xq  = tid & 7;
    const int c0  = chh * 64 + chg * 2;  // channel base within head
    const int x0  = xq * 4;
    const float* v0 = vpad + (long)bz * 196608 + (long)c0 * 1536;
    const float* v1 = v0 + 1536;
    const float* b0 = Vbias + (g * 128 + c0) * 225 + w0;
    const float* b1 = b0 + 225;

    float acc0[4] = {0.f, 0.f, 0.f, 0.f};
    float acc1[4] = {0.f, 0.f, 0.f, 0.f};

    for (int d = 0; d < ndy; ++d) {
        int hy = y + dy0 + d - 7;
        if (hy < 0 || hy > 31) continue;           // p == 0 for this dy
        const float4* r0 = (const float4*)(v0 + hy * 48 + x0);
        const float4* r1 = (const float4*)(v1 + hy * 48 + x0);
        float wa[20], wb[20];
#pragma unroll
        for (int t = 0; t < 5; ++t) {
            float4 a = r0[t], b = r1[t];
            wa[4*t+0] = a.x; wa[4*t+1] = a.y; wa[4*t+2] = a.z; wa[4*t+3] = a.w;
            wb[4*t+0] = b.x; wb[4*t+1] = b.y; wb[4*t+2] = b.z; wb[4*t+3] = b.w;
        }
        const float* par = &pa[d * 15 * 32 + x0];
        const float* vb0 = b0 + d * 15;
        const float* vb1 = b1 + d * 15;
#pragma unroll
        for (int dx = 0; dx < 15; ++dx) {
            float4 p4 = *(const float4*)&par[dx * 32];
            float ba = vb0[dx], bb = vb1[dx];
            acc0[0] += p4.x * (wa[1 + dx] + ba);
            acc0[1] += p4.y * (wa[2 + dx] + ba);
            acc0[2] += p4.z * (wa[3 + dx] + ba);
            acc0[3] += p4.w * (wa[4 + dx] + ba);
            acc1[0] += p4.x * (wb[1 + dx] + bb);
            acc1[1] += p4.y * (wb[2 + dx] + bb);
            acc1[2] += p4.z * (wb[3 + dx] + bb);
            acc1[3] += p4.w * (wb[4 + dx] + bb);
        }
    }

    float* ag = agg + ((long)n << 18) + ((long)(g * 128 + c0) << 10) + y * 32 + x0;
#pragma unroll
    for (int i = 0; i < 4; ++i) atomicAdd(&ag[i], acc0[i]);
#pragma unroll
    for (int i = 0; i < 4; ++i) atomicAdd(&ag[1024 + i], acc1[i]);
}

// ---------------------------------------------------------------------------
// ws floats: qp[1048576]@0  kp[1048576]@1048576  vpad[1572864]@2097152
//            rel/attn[1843200]@3670016  agg[1048576]@5513216   (~26.3 MB)
// ---------------------------------------------------------------------------
extern "C" void kernel_launch(void* const* d_in, const int* in_sizes, int n_in,
                              void* d_out, int out_size, void* d_ws, size_t ws_size,
                              hipStream_t stream)
{
    const float* q    = (const float*)d_in[0];
    const float* k    = (const float*)d_in[1];
    const float* v    = (const float*)d_in[2];
    const float* Wq   = (const float*)d_in[3];
    const float* bq   = (const float*)d_in[4];
    const float* Wk   = (const float*)d_in[5];
    const float* bk   = (const float*)d_in[6];
    const float* Wv   = (const float*)d_in[7];
    const float* bv   = (const float*)d_in[8];
    const float* Wrel = (const float*)d_in[9];
    const float* brel = (const float*)d_in[10];
    const float* Vb   = (const float*)d_in[11];
    const float* Wfc  = (const float*)d_in[12];
    const float* bfc  = (const float*)d_in[13];
    float* out = (float*)d_out;

    float* ws   = (float*)d_ws;
    float* qp   = ws;
    float* kp   = ws + 1048576;
    float* vpad = ws + 2097152;     // [bz 8][128 ch][32 row][48 col]
    float* rel  = ws + 3670016;     // 8*225*1024, becomes attn in place
    float* agg  = ws + 5513216;     // [n][256][1024]

    dim3 blk(256);

    // zero: vpad (padding must be 0), agg (atomic target), out (split-K FC)
    hipMemsetAsync(vpad, 0, (size_t)1572864 * 4, stream);
    hipMemsetAsync(agg, 0, (size_t)1048576 * 4, stream);
    hipMemsetAsync(out, 0, (size_t)out_size * 4, stream);

    // fused QKV projections: 16*4*12 = 768 blocks (V -> padded layout)
    qkv_kernel<<<dim3(16, 4, 12), blk, 0, stream>>>(q, k, v, Wq, Wk, Wv,
                                                    bq, bk, bv, qp, kp, vpad);

    // rel logits: 16*4*8 = 512 blocks, direct store
    gemm_kernel<<<dim3(16, 4, 8), blk, 0, stream>>>(Wrel, qp, brel, rel,
        225, 128, 28800, 2, 131072, 230400, 225, 2, 0, 1, 0);

    // scores + softmax -> attn (in place over rel): 1024 blocks
    scores_kernel<<<dim3(128, 8), blk, 0, stream>>>(qp, kp, rel);

    // PV gather + V_bias fold -> agg (atomic): 1024 blocks
    pv_kernel<<<dim3(32, 4, 8), blk, 0, stream>>>(vpad, rel, Vb, agg);

    // FC with interleaved [m][n][c] store, split-K=2: 16*4*8 = 512 blocks
    gemm_kernel<<<dim3(16, 4, 8), blk, 0, stream>>>(Wfc, agg, bfc, out,
        256, 256, 0, 1, 262144, 0, 0, 1, 6, 2, 1024);
}

// Round 9
// 219.918 us; speedup vs baseline: 1.0854x; 1.0854x over previous
//
#include <hip/hip_runtime.h>
#include <math.h>

// N=4, C=256, H=W=32, NH=2, HD=128, MAX_DIS=7, WS=15, WW=225, T=sqrt(128)
// out: [hw=1024][n=4][c=256] fp32

typedef __attribute__((ext_vector_type(8))) short short8;
typedef __attribute__((ext_vector_type(4))) float floatx4;

__device__ __forceinline__ int iclamp(int v, int lo, int hi) {
    return v < lo ? lo : (v > hi ? hi : v);
}
__device__ __forceinline__ short f2bf(float f) {
    unsigned u = __float_as_uint(f);
    unsigned r = (u + 0x7fffu + ((u >> 16) & 1u)) >> 16;
    return (short)r;
}
__device__ __forceinline__ float bf2f(short s) {
    return __uint_as_float(((unsigned)(unsigned short)s) << 16);
}

// ---------------------------------------------------------------------------
// Tiled fp32 GEMM body (unchanged from round 8)
// ---------------------------------------------------------------------------
__device__ __forceinline__
void gemm_body(const float* __restrict__ Wb, const float* __restrict__ Xb,
               const float* __restrict__ biasb, float* __restrict__ Yb,
               int M, int K, int kt0, int kt1, bool addBias, int flags,
               long storeOff, int ldI)
{
    __shared__ __align__(16) float sm[64 * 68];
    float* Ws = sm;
    float* Xs = sm + 32 * 68;

    const int row0 = blockIdx.y * 64;
    const int col0 = blockIdx.x * 64;
    const int tid = threadIdx.x;
    const int tx = tid & 15, ty = tid >> 4;

    float acc[4][4];
#pragma unroll
    for (int i = 0; i < 4; ++i)
#pragma unroll
        for (int j = 0; j < 4; ++j) acc[i][j] = 0.f;

    for (int kt = kt0; kt < kt1; ++kt) {
        const int c0 = kt * 32;
#pragma unroll
        for (int i = 0; i < 2; ++i) {
            int e = tid + i * 256;
            int dd = e >> 3, c4 = (e & 7) * 4;
            int gd = row0 + dd;
            float4 w4 = make_float4(0.f, 0.f, 0.f, 0.f);
            if (gd < M) w4 = *(const float4*)&Wb[(long)gd * K + c0 + c4];
            Ws[(c4 + 0) * 68 + dd] = w4.x;
            Ws[(c4 + 1) * 68 + dd] = w4.y;
            Ws[(c4 + 2) * 68 + dd] = w4.z;
            Ws[(c4 + 3) * 68 + dd] = w4.w;
        }
#pragma unroll
        for (int i = 0; i < 2; ++i) {
            int e = tid + i * 256;
            int cc = e >> 4, m4 = (e & 15) * 4;
            float4 x4 = *(const float4*)&Xb[((long)(c0 + cc) << 10) + col0 + m4];
            *(float4*)&Xs[cc * 64 + m4] = x4;
        }
        __syncthreads();
#pragma unroll
        for (int k = 0; k < 32; ++k) {
            const float4 a4 = *(const float4*)&Ws[k * 68 + ty * 4];
            const float4 b4 = *(const float4*)&Xs[k * 64 + tx * 4];
            float av[4] = {a4.x, a4.y, a4.z, a4.w};
            float bv[4] = {b4.x, b4.y, b4.z, b4.w};
#pragma unroll
            for (int i = 0; i < 4; ++i)
#pragma unroll
                for (int j = 0; j < 4; ++j) acc[i][j] += av[i] * bv[j];
        }
        __syncthreads();
    }

    if (flags & 8) {
        int m4 = col0 + tx * 4;
        int row = m4 >> 5, col = (m4 & 31) + 8;
#pragma unroll
        for (int i = 0; i < 4; ++i) {
            int gd = row0 + ty * 4 + i;
            float bvv = (addBias && biasb) ? biasb[gd] : 0.f;
            long off = (long)gd * 1536 + row * 48 + col;
            Yb[off + 0] = acc[i][0] + bvv;
            Yb[off + 1] = acc[i][1] + bvv;
            Yb[off + 2] = acc[i][2] + bvv;
            Yb[off + 3] = acc[i][3] + bvv;
        }
    } else if (!(flags & 2)) {
#pragma unroll
        for (int i = 0; i < 4; ++i) {
            int gd = row0 + ty * 4 + i;
            if (gd >= M) continue;
            float bvv = (addBias && biasb) ? biasb[gd] : 0.f;
            long yoff = ((long)gd << 10) + col0 + tx * 4;
            if (flags & 4) {
#pragma unroll
                for (int j = 0; j < 4; ++j)
                    atomicAdd(&Yb[yoff + j], acc[i][j] + bvv);
            } else {
                float4 r;
                r.x = acc[i][0] + bvv; r.y = acc[i][1] + bvv;
                r.z = acc[i][2] + bvv; r.w = acc[i][3] + bvv;
                *(float4*)&Yb[yoff] = r;
            }
        }
    } else {
        float* tile = sm;
#pragma unroll
        for (int i = 0; i < 4; ++i) {
            float bvv = (addBias && biasb) ? biasb[row0 + ty * 4 + i] : 0.f;
#pragma unroll
            for (int j = 0; j < 4; ++j)
                tile[(tx * 4 + j) * 68 + ty * 4 + i] = acc[i][j] + bvv;
        }
        __syncthreads();
#pragma unroll
        for (int it = 0; it < 16; ++it) {
            int e = tid + it * 256;
            int dd = e & 63, mm = e >> 6;
            long off = (long)(col0 + mm) * ldI + storeOff + row0 + dd;
            if (flags & 4) atomicAdd(&Yb[off], tile[mm * 68 + dd]);
            else Yb[off] = tile[mm * 68 + dd];
        }
    }
}

__global__ __launch_bounds__(256)
void gemm_kernel(const float* __restrict__ W, const float* __restrict__ X,
                 const float* __restrict__ bias, float* __restrict__ Y,
                 int M, int K, long wStride, int wMod,
                 long xStride, long yStride, int biasStride, int biasMod,
                 int flags, int kSplit, int ldI)
{
    int b = blockIdx.z / kSplit;
    int ks = blockIdx.z - b * kSplit;
    int ktiles = (K + 31) >> 5;
    int kt0 = ks * ktiles / kSplit, kt1 = (ks + 1) * ktiles / kSplit;
    const float* Wb = W + (long)(b % wMod) * wStride;
    const float* Xb = X + (long)b * xStride;
    const float* biasb = bias ? (bias + (long)(b % biasMod) * biasStride) : nullptr;
    float* Yb; long storeOff = 0;
    if (flags & 2) { Yb = Y; storeOff = (long)b * M; }
    else           { Yb = Y + (long)b * yStride; }
    gemm_body(Wb, Xb, biasb, Yb, M, K, kt0, kt1, ks == 0, flags, storeOff, ldI);
}

__global__ __launch_bounds__(256)
void qkv_kernel(const float* __restrict__ q, const float* __restrict__ k,
                const float* __restrict__ v,
                const float* __restrict__ Wq, const float* __restrict__ Wk,
                const float* __restrict__ Wv,
                const float* __restrict__ bq, const float* __restrict__ bk,
                const float* __restrict__ bv,
                float* __restrict__ qp, float* __restrict__ kp,
                float* __restrict__ vpad)
{
    int b = blockIdx.z;
    int sel = b >> 2, batch = b & 3;
    if (sel == 2) {
        gemm_body(Wv, v + ((long)batch << 18), bv, vpad + (long)batch * 393216,
                  256, 256, 0, 8, true, 8, 0, 0);
    } else {
        const float *W, *X, *bias; float* Y;
        if (sel == 0) { W = Wq; X = q; bias = bq; Y = qp; }
        else          { W = Wk; X = k; bias = bk; Y = kp; }
        gemm_body(W, X + ((long)batch << 18), bias, Y + ((long)batch << 18),
                  256, 256, 0, 8, true, 0, 0, 0);
    }
}

// ---------------------------------------------------------------------------
// convert: qp/kp fp32 [c][m]  ->  x-major bf16 hi/lo [bz][m][c] (128 c/head).
// q is pre-scaled by 1/sqrt(128). grid (y 32, bz 8, t 2): t=0 q, t=1 k.
// ---------------------------------------------------------------------------
__global__ __launch_bounds__(256)
void convert_kernel(const float* __restrict__ qp, const float* __restrict__ kp,
                    short* __restrict__ qhi, short* __restrict__ qlo,
                    short* __restrict__ khi, short* __restrict__ klo)
{
    __shared__ float st[32 * 129];
    const int tid = threadIdx.x;
    const int y = blockIdx.x, bz = blockIdx.y, t = blockIdx.z;
    const long hoff = (long)((bz >> 1) * 256 + (bz & 1) * 128) << 10;
    const float* src = (t ? kp : qp) + hoff + y * 32;
    const float scale = t ? 1.0f : 0.08838834764831845f;

    for (int e = tid; e < 1024; e += 256) {
        int c = e >> 3, x4 = (e & 7) * 4;
        float4 v = *(const float4*)&src[((long)c << 10) + x4];
        st[(x4 + 0) * 129 + c] = v.x;
        st[(x4 + 1) * 129 + c] = v.y;
        st[(x4 + 2) * 129 + c] = v.z;
        st[(x4 + 3) * 129 + c] = v.w;
    }
    __syncthreads();

    const int m = tid >> 3, c0 = (tid & 7) * 16;
    short h[16], l[16];
#pragma unroll
    for (int j = 0; j < 16; ++j) {
        float f = st[m * 129 + c0 + j] * scale;
        short hb = f2bf(f);
        h[j] = hb;
        l[j] = f2bf(f - bf2f(hb));
    }
    long ob = (((long)bz << 10) + y * 32 + m) * 128 + c0;
    short* oh = t ? khi : qhi;
    short* ol = t ? klo : qlo;
    *(short8*)(oh + ob)     = *(short8*)&h[0];
    *(short8*)(oh + ob + 8) = *(short8*)&h[8];
    *(short8*)(ol + ob)     = *(short8*)&l[0];
    *(short8*)(ol + ob + 8) = *(short8*)&l[8];
}

// ---------------------------------------------------------------------------
// scores via MFMA band-GEMM + softmax. block = (y, x-tile 16px, bz), 512 blk.
// Per dy: S[16q x 32k] = Q·K^T with bf16 hi/lo split (3 MFMAs per k-chunk,
// 24 MFMAs/dy), band extracted into qk LDS (pre-init -1e8), then coalesced
// rel-add, softmax (16 thr/px), normalized writeback to rel buffer.
// ---------------------------------------------------------------------------
__global__ __launch_bounds__(256)
void scores_mfma(const short* __restrict__ qhi, const short* __restrict__ qlo,
                 const short* __restrict__ khi, const short* __restrict__ klo,
                 float* __restrict__ relattn)
{
    __shared__ float qk[16 * 241];
    __shared__ float invl[16];

    const int tid = threadIdx.x;
    const int wave = tid >> 6, lane = tid & 63;
    const int y  = blockIdx.x >> 1;
    const int xt = blockIdx.x & 1;
    const int bz = blockIdx.y;
    const int x0 = xt * 16;
    float* relh = relattn + (long)bz * 230400;

    for (int e = tid; e < 16 * 241; e += 256) qk[e] = -1e8f;

    // A fragments: Q[x0 + (lane&15)][c = quad*8 + j], hi and lo
    const int n16 = lane & 15, quad = lane >> 4;
    const long qbase = (((long)bz << 10) + y * 32 + x0 + n16) * 128 + quad * 8;
    short8 a_hi[4], a_lo[4];
#pragma unroll
    for (int ch = 0; ch < 4; ++ch) {
        a_hi[ch] = *(const short8*)(qhi + qbase + ch * 32);
        a_lo[ch] = *(const short8*)(qlo + qbase + ch * 32);
    }
    __syncthreads();

    for (int dy = wave; dy < 15; dy += 4) {
        const int ky = y + dy - 7;
        if (ky < 0 || ky > 31) continue;
#pragma unroll
        for (int kxt = 0; kxt < 2; ++kxt) {
            const int kxg0 = x0 - 8 + kxt * 16;
            const int kxg = kxg0 + n16;           // may be outside [0,32): masked
            const long kb = (((long)bz << 10) + ky * 32 + kxg) * 128 + quad * 8;
            floatx4 acc = {0.f, 0.f, 0.f, 0.f};
#pragma unroll
            for (int ch = 0; ch < 4; ++ch) {
                short8 b_hi = *(const short8*)(khi + kb + ch * 32);
                short8 b_lo = *(const short8*)(klo + kb + ch * 32);
                acc = __builtin_amdgcn_mfma_f32_16x16x32_bf16(a_hi[ch], b_hi, acc, 0, 0, 0);
                acc = __builtin_amdgcn_mfma_f32_16x16x32_bf16(a_hi[ch], b_lo, acc, 0, 0, 0);
                acc = __builtin_amdgcn_mfma_f32_16x16x32_bf16(a_lo[ch], b_hi, acc, 0, 0, 0);
            }
            // D: row m = quad*4 + r (query), col n = lane&15 (key)
            if (kxg >= 0 && kxg < 32) {
#pragma unroll
                for (int r = 0; r < 4; ++r) {
                    int m = quad * 4 + r;
                    int dx = kxg - (x0 + m) + 7;
                    if (dx >= 0 && dx < 15)
                        qk[m * 241 + dy * 16 + dx] = acc[r];
                }
            }
        }
    }
    __syncthreads();

    // coalesced rel-add (invalid slots stay ~ -1e8)
    for (int e = tid; e < 3600; e += 256) {
        int px = e & 15, w = e >> 4;
        int dy2 = w / 15, dx2 = w - dy2 * 15;
        qk[px * 241 + dy2 * 16 + dx2] +=
            relh[((long)w << 10) + y * 32 + x0 + px];
    }
    __syncthreads();

    // softmax over 240 slots: 16 threads per px
    {
        int px = tid >> 4, s = tid & 15;
        float mx = -3.0e38f;
        for (int w = s; w < 240; w += 16) mx = fmaxf(mx, qk[px * 241 + w]);
#pragma unroll
        for (int msk = 8; msk; msk >>= 1) mx = fmaxf(mx, __shfl_xor(mx, msk));
        float sum = 0.f;
        for (int w = s; w < 240; w += 16) {
            float p = __expf(qk[px * 241 + w] - mx);
            qk[px * 241 + w] = p;
            sum += p;
        }
#pragma unroll
        for (int msk = 8; msk; msk >>= 1) sum += __shfl_xor(sum, msk);
        if (s == 0) invl[px] = 1.0f / sum;
    }
    __syncthreads();

    for (int e = tid; e < 3600; e += 256) {
        int px = e & 15, w = e >> 4;
        int dy2 = w / 15, dx2 = w - dy2 * 15;
        relh[((long)w << 10) + y * 32 + x0 + px] =
            qk[px * 241 + dy2 * 16 + dx2] * invl[px];
    }
}

// ---------------------------------------------------------------------------
// PV v4 (unchanged): padded V, register window, dy-half split, atomic agg.
// ---------------------------------------------------------------------------
__global__ __launch_bounds__(256)
void pv_kernel(const float* __restrict__ vpad, const float* __restrict__ attn,
               const float* __restrict__ Vbias, float* __restrict__ agg)
{
    __shared__ __align__(16) float pa[120 * 32];
    const int tid = threadIdx.x;
    const int y   = blockIdx.x;
    const int chh = blockIdx.y & 1;
    const int dyh = blockIdx.y >> 1;
    const int bz  = blockIdx.z;
    const int n = bz >> 1, g = bz & 1;

    const int dy0 = dyh * 8;
    const int ndy = dyh ? 7 : 8;
    const int w0  = dy0 * 15;
    const int nw  = ndy * 15;

    const float* ab = attn + (long)bz * 230400 + ((long)w0 << 10) + y * 32;
    for (int e = tid; e < nw * 8; e += 256) {
        int w = e >> 3, x4 = (e & 7) * 4;
        *(float4*)&pa[w * 32 + x4] = *(const float4*)&ab[((long)w << 10) + x4];
    }
    __syncthreads();

    const int chg = tid >> 3;
    const int xq  = tid & 7;
    const int c0  = chh * 64 + chg * 2;
    const int x0  = xq * 4;
    const float* v0 = vpad + (long)bz * 196608 + (long)c0 * 1536;
    const float* v1 = v0 + 1536;
    const float* b0 = Vbias + (g * 128 + c0) * 225 + w0;
    const float* b1 = b0 + 225;

    float acc0[4] = {0.f, 0.f, 0.f, 0.f};
    float acc1[4] = {0.f, 0.f, 0.f, 0.f};

    for (int d = 0; d < ndy; ++d) {
        int hy = y + dy0 + d - 7;
        if (hy < 0 || hy > 31) continue;
        const float4* r0 = (const float4*)(v0 + hy * 48 + x0);
        const float4* r1 = (const float4*)(v1 + hy * 48 + x0);
        float wa[20], wb[20];
#pragma unroll
        for (int t = 0; t < 5; ++t) {
            float4 a = r0[t], b = r1[t];
            wa[4*t+0] = a.x; wa[4*t+1] = a.y; wa[4*t+2] = a.z; wa[4*t+3] = a.w;
            wb[4*t+0] = b.x; wb[4*t+1] = b.y; wb[4*t+2] = b.z; wb[4*t+3] = b.w;
        }
        const float* par = &pa[d * 15 * 32 + x0];
        const float* vb0 = b0 + d * 15;
        const float* vb1 = b1 + d * 15;
#pragma unroll
        for (int dx = 0; dx < 15; ++dx) {
            float4 p4 = *(const float4*)&par[dx * 32];
            float ba = vb0[dx], bb = vb1[dx];
            acc0[0] += p4.x * (wa[1 + dx] + ba);
            acc0[1] += p4.y * (wa[2 + dx] + ba);
            acc0[2] += p4.z * (wa[3 + dx] + ba);
            acc0[3] += p4.w * (wa[4 + dx] + ba);
            acc1[0] += p4.x * (wb[1 + dx] + bb);
            acc1[1] += p4.y * (wb[2 + dx] + bb);
            acc1[2] += p4.z * (wb[3 + dx] + bb);
            acc1[3] += p4.w * (wb[4 + dx] + bb);
        }
    }

    float* ag = agg + ((long)n << 18) + ((long)(g * 128 + c0) << 10) + y * 32 + x0;
#pragma unroll
    for (int i = 0; i < 4; ++i) atomicAdd(&ag[i], acc0[i]);
#pragma unroll
    for (int i = 0; i < 4; ++i) atomicAdd(&ag[1024 + i], acc1[i]);
}

// ---------------------------------------------------------------------------
// ws floats: qp@0 kp@1048576 vpad@2097152(1572864) rel@3670016(1843200)
//            agg@5513216(1048576)
// bf16 (shorts, 524288 floats each): khi@5513216 klo@6037504  (alias agg:
//   dead before agg's memset)  qhi@6561792 qlo@7086080  -> ws end 7610368 fl.
// ---------------------------------------------------------------------------
extern "C" void kernel_launch(void* const* d_in, const int* in_sizes, int n_in,
                              void* d_out, int out_size, void* d_ws, size_t ws_size,
                              hipStream_t stream)
{
    const float* q    = (const float*)d_in[0];
    const float* k    = (const float*)d_in[1];
    const float* v    = (const float*)d_in[2];
    const float* Wq   = (const float*)d_in[3];
    const float* bq   = (const float*)d_in[4];
    const float* Wk   = (const float*)d_in[5];
    const float* bk   = (const float*)d_in[6];
    const float* Wv   = (const float*)d_in[7];
    const float* bv   = (const float*)d_in[8];
    const float* Wrel = (const float*)d_in[9];
    const float* brel = (const float*)d_in[10];
    const float* Vb   = (const float*)d_in[11];
    const float* Wfc  = (const float*)d_in[12];
    const float* bfc  = (const float*)d_in[13];
    float* out = (float*)d_out;

    float* ws   = (float*)d_ws;
    float* qp   = ws;
    float* kp   = ws + 1048576;
    float* vpad = ws + 2097152;
    float* rel  = ws + 3670016;
    float* agg  = ws + 5513216;
    short* khi  = (short*)(ws + 5513216);   // aliases agg (dead before memset)
    short* klo  = (short*)(ws + 6037504);
    short* qhi  = (short*)(ws + 6561792);
    short* qlo  = (short*)(ws + 7086080);

    dim3 blk(256);

    hipMemsetAsync(vpad, 0, (size_t)1572864 * 4, stream);
    hipMemsetAsync(out, 0, (size_t)out_size * 4, stream);

    // fused QKV projections: 768 blocks (V -> padded layout)
    qkv_kernel<<<dim3(16, 4, 12), blk, 0, stream>>>(q, k, v, Wq, Wk, Wv,
                                                    bq, bk, bv, qp, kp, vpad);

    // bf16 hi/lo conversion of Q (scaled) and K: 512 blocks
    convert_kernel<<<dim3(32, 8, 2), blk, 0, stream>>>(qp, kp, qhi, qlo, khi, klo);

    // rel logits: 512 blocks, direct store
    gemm_kernel<<<dim3(16, 4, 8), blk, 0, stream>>>(Wrel, qp, brel, rel,
        225, 128, 28800, 2, 131072, 230400, 225, 2, 0, 1, 0);

    // scores via MFMA + softmax -> attn (in place over rel): 512 blocks
    scores_mfma<<<dim3(64, 8), blk, 0, stream>>>(qhi, qlo, khi, klo, rel);

    // zero agg AFTER scores (khi/klo alias now dead), before pv atomics
    hipMemsetAsync(agg, 0, (size_t)1048576 * 4, stream);

    // PV gather + V_bias fold -> agg (atomic): 1024 blocks
    pv_kernel<<<dim3(32, 4, 8), blk, 0, stream>>>(vpad, rel, Vb, agg);

    // FC with interleaved [m][n][c] store, split-K=2: 512 blocks
    gemm_kernel<<<dim3(16, 4, 8), blk, 0, stream>>>(Wfc, agg, bfc, out,
        256, 256, 0, 1, 262144, 0, 0, 1, 6, 2, 1024);
}

// Round 10
// 201.374 us; speedup vs baseline: 1.1853x; 1.0921x over previous
//
#include <hip/hip_runtime.h>
#include <math.h>

// N=4, C=256, H=W=32, NH=2, HD=128, MAX_DIS=7, WS=15, WW=225, T=sqrt(128)
// out: [hw=1024][n=4][c=256] fp32

typedef __attribute__((ext_vector_type(8))) short short8;
typedef __attribute__((ext_vector_type(4))) float floatx4;

__device__ __forceinline__ int iclamp(int v, int lo, int hi) {
    return v < lo ? lo : (v > hi ? hi : v);
}
__device__ __forceinline__ short f2bf(float f) {
    unsigned u = __float_as_uint(f);
    unsigned r = (u + 0x7fffu + ((u >> 16) & 1u)) >> 16;
    return (short)r;
}
__device__ __forceinline__ float bf2f(short s) {
    return __uint_as_float(((unsigned)(unsigned short)s) << 16);
}

// ---------------------------------------------------------------------------
// fp32 GEMM (kept for rel only): Y[b][d][m] = W[d][c] X[b][c][m] + bias
// ---------------------------------------------------------------------------
__device__ __forceinline__
void gemm_body(const float* __restrict__ Wb, const float* __restrict__ Xb,
               const float* __restrict__ biasb, float* __restrict__ Yb,
               int M, int K)
{
    __shared__ __align__(16) float sm[64 * 68];
    float* Ws = sm;
    float* Xs = sm + 32 * 68;

    const int row0 = blockIdx.y * 64;
    const int col0 = blockIdx.x * 64;
    const int tid = threadIdx.x;
    const int tx = tid & 15, ty = tid >> 4;

    float acc[4][4];
#pragma unroll
    for (int i = 0; i < 4; ++i)
#pragma unroll
        for (int j = 0; j < 4; ++j) acc[i][j] = 0.f;

    const int kt1 = (K + 31) >> 5;
    for (int kt = 0; kt < kt1; ++kt) {
        const int c0 = kt * 32;
#pragma unroll
        for (int i = 0; i < 2; ++i) {
            int e = tid + i * 256;
            int dd = e >> 3, c4 = (e & 7) * 4;
            int gd = row0 + dd;
            float4 w4 = make_float4(0.f, 0.f, 0.f, 0.f);
            if (gd < M) w4 = *(const float4*)&Wb[(long)gd * K + c0 + c4];
            Ws[(c4 + 0) * 68 + dd] = w4.x;
            Ws[(c4 + 1) * 68 + dd] = w4.y;
            Ws[(c4 + 2) * 68 + dd] = w4.z;
            Ws[(c4 + 3) * 68 + dd] = w4.w;
        }
#pragma unroll
        for (int i = 0; i < 2; ++i) {
            int e = tid + i * 256;
            int cc = e >> 4, m4 = (e & 15) * 4;
            float4 x4 = *(const float4*)&Xb[((long)(c0 + cc) << 10) + col0 + m4];
            *(float4*)&Xs[cc * 64 + m4] = x4;
        }
        __syncthreads();
#pragma unroll
        for (int k = 0; k < 32; ++k) {
            const float4 a4 = *(const float4*)&Ws[k * 68 + ty * 4];
            const float4 b4 = *(const float4*)&Xs[k * 64 + tx * 4];
            float av[4] = {a4.x, a4.y, a4.z, a4.w};
            float bv[4] = {b4.x, b4.y, b4.z, b4.w};
#pragma unroll
            for (int i = 0; i < 4; ++i)
#pragma unroll
                for (int j = 0; j < 4; ++j) acc[i][j] += av[i] * bv[j];
        }
        __syncthreads();
    }

#pragma unroll
    for (int i = 0; i < 4; ++i) {
        int gd = row0 + ty * 4 + i;
        if (gd >= M) continue;
        float bvv = biasb ? biasb[gd] : 0.f;
        long yoff = ((long)gd << 10) + col0 + tx * 4;
        float4 r;
        r.x = acc[i][0] + bvv; r.y = acc[i][1] + bvv;
        r.z = acc[i][2] + bvv; r.w = acc[i][3] + bvv;
        *(float4*)&Yb[yoff] = r;
    }
}

__global__ __launch_bounds__(256)
void gemm_kernel(const float* __restrict__ W, const float* __restrict__ X,
                 const float* __restrict__ bias, float* __restrict__ Y,
                 int M, int K, long wStride, int wMod,
                 long xStride, long yStride, int biasStride, int biasMod)
{
    int b = blockIdx.z;
    gemm_body(W + (long)(b % wMod) * wStride, X + (long)b * xStride,
              bias ? (bias + (long)(b % biasMod) * biasStride) : nullptr,
              Y + (long)b * yStride, M, K);
}

// ---------------------------------------------------------------------------
// conv_kernel: build bf16 hi/lo MFMA fragment layouts.
// z in 0..11: inputs q/k/v (sel=z>>2, batch=z&3), fp32 [256 c][1024 m] ->
//   B-frag: Xhi[z*262144 + ((mt16*8+kc)*64+lane)*8+j] = X[kc*32+quad*8+j][mt16*16+(lane&15)]
// z in 12..15: weights Wq,Wk,Wv,Wfc [256 d][256 c] ->
//   A-frag: Whi[w*65536 + ((dt*8+kc)*64+lane)*8+j] = W[dt*16+(lane&15)][kc*32+quad*8+j]
// ---------------------------------------------------------------------------
__global__ __launch_bounds__(256)
void conv_kernel(const float* __restrict__ q, const float* __restrict__ k,
                 const float* __restrict__ v,
                 const float* __restrict__ Wq, const float* __restrict__ Wk,
                 const float* __restrict__ Wv, const float* __restrict__ Wfc,
                 short* __restrict__ Xhi, short* __restrict__ Xlo,
                 short* __restrict__ Whi, short* __restrict__ Wlo)
{
    const int tid = threadIdx.x;
    const int z = blockIdx.z;
    const int lane = tid & 63;
    const int n16 = lane & 15, quad = lane >> 4;

    if (z < 12) {
        __shared__ float st[64 * 33];
        const int sel = z >> 2, batch = z & 3;
        const float* X = (sel == 0 ? q : sel == 1 ? k : v) + ((long)batch << 18);
        const int mb = blockIdx.x, kc = blockIdx.y;
#pragma unroll
        for (int it = 0; it < 8; ++it) {
            int e = tid + it * 256;
            int cc = e >> 6, mm = e & 63;
            st[mm * 33 + cc] = X[((long)(kc * 32 + cc) << 10) + mb * 64 + mm];
        }
        __syncthreads();
        const int mtl = tid >> 6;
        const int m = mtl * 16 + n16;
        short h[8], l[8];
#pragma unroll
        for (int j = 0; j < 8; ++j) {
            float f = st[m * 33 + quad * 8 + j];
            short hb = f2bf(f);
            h[j] = hb;
            l[j] = f2bf(f - bf2f(hb));
        }
        int mt16 = mb * 4 + mtl;
        long off = (long)z * 262144 + (((long)(mt16 * 8 + kc) * 64) + lane) * 8;
        *(short8*)(Xhi + off) = *(short8*)&h[0];
        *(short8*)(Xlo + off) = *(short8*)&l[0];
    } else {
        if (tid >= 64) return;
        const int w = z - 12;
        const float* W = (w == 0 ? Wq : w == 1 ? Wk : w == 2 ? Wv : Wfc);
        const int dt = blockIdx.x, kc = blockIdx.y;
        const int d = dt * 16 + n16, cb = kc * 32 + quad * 8;
        float4 w0 = *(const float4*)&W[d * 256 + cb];
        float4 w1 = *(const float4*)&W[d * 256 + cb + 4];
        float f[8] = {w0.x, w0.y, w0.z, w0.w, w1.x, w1.y, w1.z, w1.w};
        short h[8], l[8];
#pragma unroll
        for (int j = 0; j < 8; ++j) {
            short hb = f2bf(f[j]);
            h[j] = hb;
            l[j] = f2bf(f[j] - bf2f(hb));
        }
        long off = (long)w * 65536 + (((long)(dt * 8 + kc) * 64) + lane) * 8;
        *(short8*)(Whi + off) = *(short8*)&h[0];
        *(short8*)(Wlo + off) = *(short8*)&l[0];
    }
}

// ---------------------------------------------------------------------------
// mfma_proj: Y = W·X for q/k/v with hi/lo split (3 MFMAs per k-chunk).
// grid (mb 16, db 4, z 12); wave = d-tile. Epilogues: qp/kp direct, V->vpad.
// ---------------------------------------------------------------------------
__global__ __launch_bounds__(256)
void mfma_proj(const short* __restrict__ Xhi, const short* __restrict__ Xlo,
               const short* __restrict__ Whi, const short* __restrict__ Wlo,
               const float* __restrict__ bq, const float* __restrict__ bk,
               const float* __restrict__ bv,
               float* __restrict__ qp, float* __restrict__ kp,
               float* __restrict__ vpad)
{
    const int tid = threadIdx.x;
    const int wave = tid >> 6, lane = tid & 63;
    const int n16 = lane & 15, quad = lane >> 4;
    const int mb = blockIdx.x, db = blockIdx.y, z = blockIdx.z;
    const int sel = z >> 2, batch = z & 3;
    const int dt = db * 4 + wave;

    const short* Ah = Whi + (long)sel * 65536 + ((long)(dt * 8) * 64 + lane) * 8;
    const short* Al = Wlo + (long)sel * 65536 + ((long)(dt * 8) * 64 + lane) * 8;
    short8 ahi[8], alo[8];
#pragma unroll
    for (int kc = 0; kc < 8; ++kc) {
        ahi[kc] = *(const short8*)(Ah + kc * 512);
        alo[kc] = *(const short8*)(Al + kc * 512);
    }
    const short* Bh = Xhi + (long)z * 262144;
    const short* Bl = Xlo + (long)z * 262144;

    const float* bias = (sel == 0 ? bq : sel == 1 ? bk : bv);
    float4 bv4 = *(const float4*)&bias[dt * 16 + quad * 4];
    float bb[4] = {bv4.x, bv4.y, bv4.z, bv4.w};

#pragma unroll
    for (int mtl = 0; mtl < 4; ++mtl) {
        const int mt16 = mb * 4 + mtl;
        floatx4 acc = {0.f, 0.f, 0.f, 0.f};
#pragma unroll
        for (int kc = 0; kc < 8; ++kc) {
            long bo = ((long)(mt16 * 8 + kc) * 64 + lane) * 8;
            short8 bh = *(const short8*)(Bh + bo);
            short8 bl = *(const short8*)(Bl + bo);
            acc = __builtin_amdgcn_mfma_f32_16x16x32_bf16(ahi[kc], bh, acc, 0, 0, 0);
            acc = __builtin_amdgcn_mfma_f32_16x16x32_bf16(ahi[kc], bl, acc, 0, 0, 0);
            acc = __builtin_amdgcn_mfma_f32_16x16x32_bf16(alo[kc], bh, acc, 0, 0, 0);
        }
        const int m = mt16 * 16 + n16;
        if (sel < 2) {
            float* Y = (sel ? kp : qp) + ((long)batch << 18);
#pragma unroll
            for (int r = 0; r < 4; ++r)
                Y[((long)(dt * 16 + quad * 4 + r) << 10) + m] = acc[r] + bb[r];
        } else {
            float* Y = vpad + (long)batch * 393216;
            const int row = m >> 5, col = (m & 31) + 8;
#pragma unroll
            for (int r = 0; r < 4; ++r)
                Y[(long)(dt * 16 + quad * 4 + r) * 1536 + row * 48 + col] = acc[r] + bb[r];
        }
    }
}

// ---------------------------------------------------------------------------
// aggconv: agg fp32 [n][256 c][1024 m] -> B-frag hi/lo (4 tensors)
// ---------------------------------------------------------------------------
__global__ __launch_bounds__(256)
void aggconv_kernel(const float* __restrict__ agg,
                    short* __restrict__ Ahi, short* __restrict__ Alo)
{
    __shared__ float st[64 * 33];
    const int tid = threadIdx.x;
    const int mb = blockIdx.x, kc = blockIdx.y, nz = blockIdx.z;
    const float* X = agg + ((long)nz << 18);
#pragma unroll
    for (int it = 0; it < 8; ++it) {
        int e = tid + it * 256;
        int cc = e >> 6, mm = e & 63;
        st[mm * 33 + cc] = X[((long)(kc * 32 + cc) << 10) + mb * 64 + mm];
    }
    __syncthreads();
    const int lane = tid & 63, mtl = tid >> 6;
    const int n16 = lane & 15, quad = lane >> 4;
    const int m = mtl * 16 + n16;
    short h[8], l[8];
#pragma unroll
    for (int j = 0; j < 8; ++j) {
        float f = st[m * 33 + quad * 8 + j];
        short hb = f2bf(f);
        h[j] = hb;
        l[j] = f2bf(f - bf2f(hb));
    }
    int mt16 = mb * 4 + mtl;
    long off = (long)nz * 262144 + (((long)(mt16 * 8 + kc) * 64) + lane) * 8;
    *(short8*)(Ahi + off) = *(short8*)&h[0];
    *(short8*)(Alo + off) = *(short8*)&l[0];
}

// ---------------------------------------------------------------------------
// mfma_fc: out[m][n][d] = Wfc·agg + bfc, interleaved store via LDS transpose.
// grid (mb 16, db 4, n 4).
// ---------------------------------------------------------------------------
__global__ __launch_bounds__(256)
void mfma_fc(const short* __restrict__ Ahi, const short* __restrict__ Alo,
             const short* __restrict__ Whi, const short* __restrict__ Wlo,
             const float* __restrict__ bfc, float* __restrict__ out)
{
    __shared__ float tile[64 * 68];
    const int tid = threadIdx.x;
    const int wave = tid >> 6, lane = tid & 63;
    const int n16 = lane & 15, quad = lane >> 4;
    const int mb = blockIdx.x, db = blockIdx.y, nz = blockIdx.z;
    const int dt = db * 4 + wave;

    const short* Ah = Whi + (long)3 * 65536 + ((long)(dt * 8) * 64 + lane) * 8;
    const short* Al = Wlo + (long)3 * 65536 + ((long)(dt * 8) * 64 + lane) * 8;
    short8 ahi[8], alo[8];
#pragma unroll
    for (int kc = 0; kc < 8; ++kc) {
        ahi[kc] = *(const short8*)(Ah + kc * 512);
        alo[kc] = *(const short8*)(Al + kc * 512);
    }
    const short* Bh = Ahi + (long)nz * 262144;
    const short* Bl = Alo + (long)nz * 262144;

    float4 bv4 = *(const float4*)&bfc[dt * 16 + quad * 4];
    float bb[4] = {bv4.x, bv4.y, bv4.z, bv4.w};

#pragma unroll
    for (int mtl = 0; mtl < 4; ++mtl) {
        const int mt16 = mb * 4 + mtl;
        floatx4 acc = {0.f, 0.f, 0.f, 0.f};
#pragma unroll
        for (int kc = 0; kc < 8; ++kc) {
            long bo = ((long)(mt16 * 8 + kc) * 64 + lane) * 8;
            short8 bh = *(const short8*)(Bh + bo);
            short8 bl = *(const short8*)(Bl + bo);
            acc = __builtin_amdgcn_mfma_f32_16x16x32_bf16(ahi[kc], bh, acc, 0, 0, 0);
            acc = __builtin_amdgcn_mfma_f32_16x16x32_bf16(ahi[kc], bl, acc, 0, 0, 0);
            acc = __builtin_amdgcn_mfma_f32_16x16x32_bf16(alo[kc], bh, acc, 0, 0, 0);
        }
        const int ml = mtl * 16 + n16;
        const int dl = wave * 16 + quad * 4;
#pragma unroll
        for (int r = 0; r < 4; ++r)
            tile[ml * 68 + dl + r] = acc[r] + bb[r];
    }
    __syncthreads();
#pragma unroll
    for (int it = 0; it < 16; ++it) {
        int e = tid + it * 256;
        int dd = e & 63, mm = e >> 6;
        out[(long)(mb * 64 + mm) * 1024 + nz * 256 + db * 64 + dd] = tile[mm * 68 + dd];
    }
}

// ---------------------------------------------------------------------------
// convert: qp/kp fp32 [c][m] -> x-major bf16 hi/lo [bz][m][c] for scores.
// Scale 1/T now applied to K (keeps qp clean for the fp32 rel GEMM).
// ---------------------------------------------------------------------------
__global__ __launch_bounds__(256)
void convert_kernel(const float* __restrict__ qp, const float* __restrict__ kp,
                    short* __restrict__ qhi, short* __restrict__ qlo,
                    short* __restrict__ khi, short* __restrict__ klo)
{
    __shared__ float st[32 * 129];
    const int tid = threadIdx.x;
    const int y = blockIdx.x, bz = blockIdx.y, t = blockIdx.z;
    const long hoff = (long)((bz >> 1) * 256 + (bz & 1) * 128) << 10;
    const float* src = (t ? kp : qp) + hoff + y * 32;
    const float scale = t ? 0.08838834764831845f : 1.0f;

    for (int e = tid; e < 1024; e += 256) {
        int c = e >> 3, x4 = (e & 7) * 4;
        float4 v = *(const float4*)&src[((long)c << 10) + x4];
        st[(x4 + 0) * 129 + c] = v.x;
        st[(x4 + 1) * 129 + c] = v.y;
        st[(x4 + 2) * 129 + c] = v.z;
        st[(x4 + 3) * 129 + c] = v.w;
    }
    __syncthreads();

    const int m = tid >> 3, c0 = (tid & 7) * 16;
    short h[16], l[16];
#pragma unroll
    for (int j = 0; j < 16; ++j) {
        float f = st[m * 129 + c0 + j] * scale;
        short hb = f2bf(f);
        h[j] = hb;
        l[j] = f2bf(f - bf2f(hb));
    }
    long ob = (((long)bz << 10) + y * 32 + m) * 128 + c0;
    short* oh = t ? khi : qhi;
    short* ol = t ? klo : qlo;
    *(short8*)(oh + ob)     = *(short8*)&h[0];
    *(short8*)(oh + ob + 8) = *(short8*)&h[8];
    *(short8*)(ol + ob)     = *(short8*)&l[0];
    *(short8*)(ol + ob + 8) = *(short8*)&l[8];
}

// ---------------------------------------------------------------------------
// scores via MFMA band-GEMM + softmax (unchanged from round 9)
// ---------------------------------------------------------------------------
__global__ __launch_bounds__(256)
void scores_mfma(const short* __restrict__ qhi, const short* __restrict__ qlo,
                 const short* __restrict__ khi, const short* __restrict__ klo,
                 float* __restrict__ relattn)
{
    __shared__ float qk[16 * 241];
    __shared__ float invl[16];

    const int tid = threadIdx.x;
    const int wave = tid >> 6, lane = tid & 63;
    const int y  = blockIdx.x >> 1;
    const int xt = blockIdx.x & 1;
    const int bz = blockIdx.y;
    const int x0 = xt * 16;
    float* relh = relattn + (long)bz * 230400;

    for (int e = tid; e < 16 * 241; e += 256) qk[e] = -1e8f;

    const int n16 = lane & 15, quad = lane >> 4;
    const long qbase = (((long)bz << 10) + y * 32 + x0 + n16) * 128 + quad * 8;
    short8 a_hi[4], a_lo[4];
#pragma unroll
    for (int ch = 0; ch < 4; ++ch) {
        a_hi[ch] = *(const short8*)(qhi + qbase + ch * 32);
        a_lo[ch] = *(const short8*)(qlo + qbase + ch * 32);
    }
    __syncthreads();

    for (int dy = wave; dy < 15; dy += 4) {
        const int ky = y + dy - 7;
        if (ky < 0 || ky > 31) continue;
#pragma unroll
        for (int kxt = 0; kxt < 2; ++kxt) {
            const int kxg = x0 - 8 + kxt * 16 + n16;
            const long kb = (((long)bz << 10) + ky * 32 + kxg) * 128 + quad * 8;
            floatx4 acc = {0.f, 0.f, 0.f, 0.f};
#pragma unroll
            for (int ch = 0; ch < 4; ++ch) {
                short8 b_hi = *(const short8*)(khi + kb + ch * 32);
                short8 b_lo = *(const short8*)(klo + kb + ch * 32);
                acc = __builtin_amdgcn_mfma_f32_16x16x32_bf16(a_hi[ch], b_hi, acc, 0, 0, 0);
                acc = __builtin_amdgcn_mfma_f32_16x16x32_bf16(a_hi[ch], b_lo, acc, 0, 0, 0);
                acc = __builtin_amdgcn_mfma_f32_16x16x32_bf16(a_lo[ch], b_hi, acc, 0, 0, 0);
            }
            if (kxg >= 0 && kxg < 32) {
#pragma unroll
                for (int r = 0; r < 4; ++r) {
                    int m = quad * 4 + r;
                    int dx = kxg - (x0 + m) + 7;
                    if (dx >= 0 && dx < 15)
                        qk[m * 241 + dy * 16 + dx] = acc[r];
                }
            }
        }
    }
    __syncthreads();

    for (int e = tid; e < 3600; e += 256) {
        int px = e & 15, w = e >> 4;
        int dy2 = w / 15, dx2 = w - dy2 * 15;
        qk[px * 241 + dy2 * 16 + dx2] +=
            relh[((long)w << 10) + y * 32 + x0 + px];
    }
    __syncthreads();

    {
        int px = tid >> 4, s = tid & 15;
        float mx = -3.0e38f;
        for (int w = s; w < 240; w += 16) mx = fmaxf(mx, qk[px * 241 + w]);
#pragma unroll
        for (int msk = 8; msk; msk >>= 1) mx = fmaxf(mx, __shfl_xor(mx, msk));
        float sum = 0.f;
        for (int w = s; w < 240; w += 16) {
            float p = __expf(qk[px * 241 + w] - mx);
            qk[px * 241 + w] = p;
            sum += p;
        }
#pragma unroll
        for (int msk = 8; msk; msk >>= 1) sum += __shfl_xor(sum, msk);
        if (s == 0) invl[px] = 1.0f / sum;
    }
    __syncthreads();

    for (int e = tid; e < 3600; e += 256) {
        int px = e & 15, w = e >> 4;
        int dy2 = w / 15, dx2 = w - dy2 * 15;
        relh[((long)w << 10) + y * 32 + x0 + px] =
            qk[px * 241 + dy2 * 16 + dx2] * invl[px];
    }
}

// ---------------------------------------------------------------------------
// PV v4 (unchanged): padded V, register window, dy-half split, atomic agg.
// ---------------------------------------------------------------------------
__global__ __launch_bounds__(256)
void pv_kernel(const float* __restrict__ vpad, const float* __restrict__ attn,
               const float* __restrict__ Vbias, float* __restrict__ agg)
{
    __shared__ __align__(16) float pa[120 * 32];
    const int tid = threadIdx.x;
    const int y   = blockIdx.x;
    const int chh = blockIdx.y & 1;
    const int dyh = blockIdx.y >> 1;
    const int bz  = blockIdx.z;
    const int n = bz >> 1, g = bz & 1;

    const int dy0 = dyh * 8;
    const int ndy = dyh ? 7 : 8;
    const int w0  = dy0 * 15;
    const int nw  = ndy * 15;

    const float* ab = attn + (long)bz * 230400 + ((long)w0 << 10) + y * 32;
    for (int e = tid; e < nw * 8; e += 256) {
        int w = e >> 3, x4 = (e & 7) * 4;
        *(float4*)&pa[w * 32 + x4] = *(const float4*)&ab[((long)w << 10) + x4];
    }
    __syncthreads();

    const int chg = tid >> 3;
    const int xq  = tid & 7;
    const int c0  = chh * 64 + chg * 2;
    const int x0  = xq * 4;
    const float* v0 = vpad + (long)bz * 196608 + (long)c0 * 1536;
    const float* v1 = v0 + 1536;
    const float* b0 = Vbias + (g * 128 + c0) * 225 + w0;
    const float* b1 = b0 + 225;

    float acc0[4] = {0.f, 0.f, 0.f, 0.f};
    float acc1[4] = {0.f, 0.f, 0.f, 0.f};

    for (int d = 0; d < ndy; ++d) {
        int hy = y + dy0 + d - 7;
        if (hy < 0 || hy > 31) continue;
        const float4* r0 = (const float4*)(v0 + hy * 48 + x0);
        const float4* r1 = (const float4*)(v1 + hy * 48 + x0);
        float wa[20], wb[20];
#pragma unroll
        for (int t = 0; t < 5; ++t) {
            float4 a = r0[t], b = r1[t];
            wa[4*t+0] = a.x; wa[4*t+1] = a.y; wa[4*t+2] = a.z; wa[4*t+3] = a.w;
            wb[4*t+0] = b.x; wb[4*t+1] = b.y; wb[4*t+2] = b.z; wb[4*t+3] = b.w;
        }
        const float* par = &pa[d * 15 * 32 + x0];
        const float* vb0 = b0 + d * 15;
        const float* vb1 = b1 + d * 15;
#pragma unroll
        for (int dx = 0; dx < 15; ++dx) {
            float4 p4 = *(const float4*)&par[dx * 32];
            float ba = vb0[dx], bb = vb1[dx];
            acc0[0] += p4.x * (wa[1 + dx] + ba);
            acc0[1] += p4.y * (wa[2 + dx] + ba);
            acc0[2] += p4.z * (wa[3 + dx] + ba);
            acc0[3] += p4.w * (wa[4 + dx] + ba);
            acc1[0] += p4.x * (wb[1 + dx] + bb);
            acc1[1] += p4.y * (wb[2 + dx] + bb);
            acc1[2] += p4.z * (wb[3 + dx] + bb);
            acc1[3] += p4.w * (wb[4 + dx] + bb);
        }
    }

    float* ag = agg + ((long)n << 18) + ((long)(g * 128 + c0) << 10) + y * 32 + x0;
#pragma unroll
    for (int i = 0; i < 4; ++i) atomicAdd(&ag[i], acc0[i]);
#pragma unroll
    for (int i = 0; i < 4; ++i) atomicAdd(&ag[1024 + i], acc1[i]);
}

// ---------------------------------------------------------------------------
// ws floats: qp@0 kp@1048576 vpad@2097152(1572864) agg@3670016(1048576)
//   rel@4718592(1843200)  qhi@6561792 qlo@7086080 khi@7610368 klo@8134656
//   Xhi@8658944(1572864) Xlo@10231808 Whi@11804672(131072) Wlo@11935744
//   AGhi@12066816(524288) AGlo@12591104  -> end 13115392 floats (~52 MB)
// ---------------------------------------------------------------------------
extern "C" void kernel_launch(void* const* d_in, const int* in_sizes, int n_in,
                              void* d_out, int out_size, void* d_ws, size_t ws_size,
                              hipStream_t stream)
{
    const float* q    = (const float*)d_in[0];
    const float* k    = (const float*)d_in[1];
    const float* v    = (const float*)d_in[2];
    const float* Wq   = (const float*)d_in[3];
    const float* bq   = (const float*)d_in[4];
    const float* Wk   = (const float*)d_in[5];
    const float* bk   = (const float*)d_in[6];
    const float* Wv   = (const float*)d_in[7];
    const float* bv   = (const float*)d_in[8];
    const float* Wrel = (const float*)d_in[9];
    const float* brel = (const float*)d_in[10];
    const float* Vb   = (const float*)d_in[11];
    const float* Wfc  = (const float*)d_in[12];
    const float* bfc  = (const float*)d_in[13];
    float* out = (float*)d_out;

    float* ws   = (float*)d_ws;
    float* qp   = ws;
    float* kp   = ws + 1048576;
    float* vpad = ws + 2097152;
    float* agg  = ws + 3670016;
    float* rel  = ws + 4718592;
    short* qhi  = (short*)(ws + 6561792);
    short* qlo  = (short*)(ws + 7086080);
    short* khi  = (short*)(ws + 7610368);
    short* klo  = (short*)(ws + 8134656);
    short* Xhi  = (short*)(ws + 8658944);
    short* Xlo  = (short*)(ws + 10231808);
    short* Whi  = (short*)(ws + 11804672);
    short* Wlo  = (short*)(ws + 11935744);
    short* AGhi = (short*)(ws + 12066816);
    short* AGlo = (short*)(ws + 12591104);

    dim3 blk(256);

    // single memset: vpad (pad zeros) + agg (pv atomic target), contiguous
    hipMemsetAsync(vpad, 0, (size_t)(1572864 + 1048576) * 4, stream);

    // fragment conversion: inputs (z 0..11) + weights (z 12..15)
    conv_kernel<<<dim3(16, 8, 16), blk, 0, stream>>>(q, k, v, Wq, Wk, Wv, Wfc,
                                                     Xhi, Xlo, Whi, Wlo);

    // QKV projections via MFMA: 16*4*12 = 768 blocks
    mfma_proj<<<dim3(16, 4, 12), blk, 0, stream>>>(Xhi, Xlo, Whi, Wlo,
                                                   bq, bk, bv, qp, kp, vpad);

    // x-major bf16 conversion of qp (unscaled) / kp (scaled): 512 blocks
    convert_kernel<<<dim3(32, 8, 2), blk, 0, stream>>>(qp, kp, qhi, qlo, khi, klo);

    // rel logits (fp32): 512 blocks
    gemm_kernel<<<dim3(16, 4, 8), blk, 0, stream>>>(Wrel, qp, brel, rel,
        225, 128, 28800, 2, 131072, 230400, 225, 2);

    // scores via MFMA + softmax -> attn (in place over rel): 512 blocks
    scores_mfma<<<dim3(64, 8), blk, 0, stream>>>(qhi, qlo, khi, klo, rel);

    // PV gather + V_bias fold -> agg (atomic): 1024 blocks
    pv_kernel<<<dim3(32, 4, 8), blk, 0, stream>>>(vpad, rel, Vb, agg);

    // agg -> fragment layout: 512 blocks
    aggconv_kernel<<<dim3(16, 8, 4), blk, 0, stream>>>(agg, AGhi, AGlo);

    // FC via MFMA, interleaved [m][n][c] store: 256 blocks
    mfma_fc<<<dim3(16, 4, 4), blk, 0, stream>>>(AGhi, AGlo, Whi, Wlo, bfc, out);
}

// Round 11
// 195.858 us; speedup vs baseline: 1.2187x; 1.0282x over previous
//
#include <hip/hip_runtime.h>
#include <math.h>

// N=4, C=256, H=W=32, NH=2, HD=128, MAX_DIS=7, WS=15, WW=225, T=sqrt(128)
// out: [hw=1024][n=4][c=256] fp32

typedef __attribute__((ext_vector_type(8))) short short8;
typedef __attribute__((ext_vector_type(4))) float floatx4;

__device__ __forceinline__ short f2bf(float f) {
    unsigned u = __float_as_uint(f);
    unsigned r = (u + 0x7fffu + ((u >> 16) & 1u)) >> 16;
    return (short)r;
}
__device__ __forceinline__ float bf2f(short s) {
    return __uint_as_float(((unsigned)(unsigned short)s) << 16);
}

// ---------------------------------------------------------------------------
// conv_kernel: build bf16 hi/lo MFMA fragment layouts.
// z 0..11 : inputs q/k/v  -> B-frags Xhi/Xlo
// z 12..15: weights Wq,Wk,Wv,Wfc -> A-frags Whi/Wlo
// z 16..17: Wrel per head -> A-frags Wrelhi/Wrello (15 w-tiles, zero-padded)
// ---------------------------------------------------------------------------
__global__ __launch_bounds__(256)
void conv_kernel(const float* __restrict__ q, const float* __restrict__ k,
                 const float* __restrict__ v,
                 const float* __restrict__ Wq, const float* __restrict__ Wk,
                 const float* __restrict__ Wv, const float* __restrict__ Wfc,
                 const float* __restrict__ Wrel,
                 short* __restrict__ Xhi, short* __restrict__ Xlo,
                 short* __restrict__ Whi, short* __restrict__ Wlo,
                 short* __restrict__ Wrh, short* __restrict__ Wrl)
{
    const int tid = threadIdx.x;
    const int z = blockIdx.z;
    const int lane = tid & 63;
    const int n16 = lane & 15, quad = lane >> 4;

    if (z < 12) {
        __shared__ float st[64 * 33];
        const int sel = z >> 2, batch = z & 3;
        const float* X = (sel == 0 ? q : sel == 1 ? k : v) + ((long)batch << 18);
        const int mb = blockIdx.x, kc = blockIdx.y;
#pragma unroll
        for (int it = 0; it < 8; ++it) {
            int e = tid + it * 256;
            int cc = e >> 6, mm = e & 63;
            st[mm * 33 + cc] = X[((long)(kc * 32 + cc) << 10) + mb * 64 + mm];
        }
        __syncthreads();
        const int mtl = tid >> 6;
        const int m = mtl * 16 + n16;
        short h[8], l[8];
#pragma unroll
        for (int j = 0; j < 8; ++j) {
            float f = st[m * 33 + quad * 8 + j];
            short hb = f2bf(f);
            h[j] = hb;
            l[j] = f2bf(f - bf2f(hb));
        }
        int mt16 = mb * 4 + mtl;
        long off = (long)z * 262144 + (((long)(mt16 * 8 + kc) * 64) + lane) * 8;
        *(short8*)(Xhi + off) = *(short8*)&h[0];
        *(short8*)(Xlo + off) = *(short8*)&l[0];
    } else if (z < 16) {
        if (tid >= 64) return;
        const int w = z - 12;
        const float* W = (w == 0 ? Wq : w == 1 ? Wk : w == 2 ? Wv : Wfc);
        const int dt = blockIdx.x, kc = blockIdx.y;
        const int d = dt * 16 + n16, cb = kc * 32 + quad * 8;
        float4 w0 = *(const float4*)&W[d * 256 + cb];
        float4 w1 = *(const float4*)&W[d * 256 + cb + 4];
        float f[8] = {w0.x, w0.y, w0.z, w0.w, w1.x, w1.y, w1.z, w1.w};
        short h[8], l[8];
#pragma unroll
        for (int j = 0; j < 8; ++j) {
            short hb = f2bf(f[j]);
            h[j] = hb;
            l[j] = f2bf(f[j] - bf2f(hb));
        }
        long off = (long)w * 65536 + (((long)(dt * 8 + kc) * 64) + lane) * 8;
        *(short8*)(Whi + off) = *(short8*)&h[0];
        *(short8*)(Wlo + off) = *(short8*)&l[0];
    } else {
        if (tid >= 64) return;
        const int g = z - 16;
        const int wt = blockIdx.x, kc = blockIdx.y;
        if (wt >= 15 || kc >= 4) return;
        const int w = wt * 16 + n16;         // 0..239, valid < 225
        const int cb = kc * 32 + quad * 8;
        float f[8] = {0.f, 0.f, 0.f, 0.f, 0.f, 0.f, 0.f, 0.f};
        if (w < 225) {
            float4 w0 = *(const float4*)&Wrel[(long)(g * 225 + w) * 128 + cb];
            float4 w1 = *(const float4*)&Wrel[(long)(g * 225 + w) * 128 + cb + 4];
            f[0] = w0.x; f[1] = w0.y; f[2] = w0.z; f[3] = w0.w;
            f[4] = w1.x; f[5] = w1.y; f[6] = w1.z; f[7] = w1.w;
        }
        short h[8], l[8];
#pragma unroll
        for (int j = 0; j < 8; ++j) {
            short hb = f2bf(f[j]);
            h[j] = hb;
            l[j] = f2bf(f[j] - bf2f(hb));
        }
        long off = (long)g * 30720 + (((long)(wt * 4 + kc) * 64) + lane) * 8;
        *(short8*)(Wrh + off) = *(short8*)&h[0];
        *(short8*)(Wrl + off) = *(short8*)&l[0];
    }
}

// ---------------------------------------------------------------------------
// mfma_proj: Y = W·X for q/k/v with hi/lo split (3 MFMAs per k-chunk).
// grid (mb 16, db 4, z 12). Epilogues:
//   sel 0/1: LDS transpose -> x-major bf16 hi/lo (q unscaled, k * 1/T)
//   sel 2  : fp32 -> padded vpad layout
// ---------------------------------------------------------------------------
__global__ __launch_bounds__(256)
void mfma_proj(const short* __restrict__ Xhi, const short* __restrict__ Xlo,
               const short* __restrict__ Whi, const short* __restrict__ Wlo,
               const float* __restrict__ bq, const float* __restrict__ bk,
               const float* __restrict__ bv,
               short* __restrict__ qhi, short* __restrict__ qlo,
               short* __restrict__ khi, short* __restrict__ klo,
               float* __restrict__ vpad)
{
    __shared__ float tile[64 * 65];
    const int tid = threadIdx.x;
    const int wave = tid >> 6, lane = tid & 63;
    const int n16 = lane & 15, quad = lane >> 4;
    const int mb = blockIdx.x, db = blockIdx.y, z = blockIdx.z;
    const int sel = z >> 2, batch = z & 3;
    const int dt = db * 4 + wave;

    const short* Ah = Whi + (long)sel * 65536 + ((long)(dt * 8) * 64 + lane) * 8;
    const short* Al = Wlo + (long)sel * 65536 + ((long)(dt * 8) * 64 + lane) * 8;
    short8 ahi[8], alo[8];
#pragma unroll
    for (int kc = 0; kc < 8; ++kc) {
        ahi[kc] = *(const short8*)(Ah + kc * 512);
        alo[kc] = *(const short8*)(Al + kc * 512);
    }
    const short* Bh = Xhi + (long)z * 262144;
    const short* Bl = Xlo + (long)z * 262144;

    const float* bias = (sel == 0 ? bq : sel == 1 ? bk : bv);
    float4 bv4 = *(const float4*)&bias[dt * 16 + quad * 4];
    float bb[4] = {bv4.x, bv4.y, bv4.z, bv4.w};

    if (sel == 2) {
#pragma unroll
        for (int mtl = 0; mtl < 4; ++mtl) {
            const int mt16 = mb * 4 + mtl;
            floatx4 acc = {0.f, 0.f, 0.f, 0.f};
#pragma unroll
            for (int kc = 0; kc < 8; ++kc) {
                long bo = ((long)(mt16 * 8 + kc) * 64 + lane) * 8;
                short8 bh = *(const short8*)(Bh + bo);
                short8 bl = *(const short8*)(Bl + bo);
                acc = __builtin_amdgcn_mfma_f32_16x16x32_bf16(ahi[kc], bh, acc, 0, 0, 0);
                acc = __builtin_amdgcn_mfma_f32_16x16x32_bf16(ahi[kc], bl, acc, 0, 0, 0);
                acc = __builtin_amdgcn_mfma_f32_16x16x32_bf16(alo[kc], bh, acc, 0, 0, 0);
            }
            const int m = mt16 * 16 + n16;
            float* Y = vpad + (long)batch * 393216;
            const int row = m >> 5, col = (m & 31) + 8;
#pragma unroll
            for (int r = 0; r < 4; ++r)
                Y[(long)(dt * 16 + quad * 4 + r) * 1536 + row * 48 + col] = acc[r] + bb[r];
        }
        return;
    }

#pragma unroll
    for (int mtl = 0; mtl < 4; ++mtl) {
        const int mt16 = mb * 4 + mtl;
        floatx4 acc = {0.f, 0.f, 0.f, 0.f};
#pragma unroll
        for (int kc = 0; kc < 8; ++kc) {
            long bo = ((long)(mt16 * 8 + kc) * 64 + lane) * 8;
            short8 bh = *(const short8*)(Bh + bo);
            short8 bl = *(const short8*)(Bl + bo);
            acc = __builtin_amdgcn_mfma_f32_16x16x32_bf16(ahi[kc], bh, acc, 0, 0, 0);
            acc = __builtin_amdgcn_mfma_f32_16x16x32_bf16(ahi[kc], bl, acc, 0, 0, 0);
            acc = __builtin_amdgcn_mfma_f32_16x16x32_bf16(alo[kc], bh, acc, 0, 0, 0);
        }
        const int ml = mtl * 16 + n16;
        const int cl = wave * 16 + quad * 4;
#pragma unroll
        for (int r = 0; r < 4; ++r)
            tile[ml * 65 + cl + r] = acc[r] + bb[r];
    }
    __syncthreads();

    const float scale = (sel == 1) ? 0.08838834764831845f : 1.0f;
    const int m_l = tid >> 2, c16 = (tid & 3) * 16;
    const int m = mb * 64 + m_l;
    const int cglob = db * 64 + c16;
    const int g = cglob >> 7, ch = cglob & 127;
    const long base = (((long)(batch * 2 + g) << 10) + m) * 128 + ch;
    short h[16], l[16];
#pragma unroll
    for (int j = 0; j < 16; ++j) {
        float f = tile[m_l * 65 + c16 + j] * scale;
        short hb = f2bf(f);
        h[j] = hb;
        l[j] = f2bf(f - bf2f(hb));
    }
    short* oh = sel ? khi : qhi;
    short* ol = sel ? klo : qlo;
    *(short8*)(oh + base)     = *(short8*)&h[0];
    *(short8*)(oh + base + 8) = *(short8*)&h[8];
    *(short8*)(ol + base)     = *(short8*)&l[0];
    *(short8*)(ol + base + 8) = *(short8*)&l[8];
}

// ---------------------------------------------------------------------------
// rel_mfma: rel[bz][w][m] = Wrel[g]·q[bz] + brel.  grid (mb 16, wq 4, bz 8).
// Wave wt = wq*4+wave (wt 15 idle). q's x-major hi/lo tensor is the B-frag.
// ---------------------------------------------------------------------------
__global__ __launch_bounds__(256)
void rel_mfma(const short* __restrict__ qhi, const short* __restrict__ qlo,
              const short* __restrict__ Wrh, const short* __restrict__ Wrl,
              const float* __restrict__ brel, float* __restrict__ rel)
{
    const int tid = threadIdx.x;
    const int wave = tid >> 6, lane = tid & 63;
    const int n16 = lane & 15, quad = lane >> 4;
    const int mb = blockIdx.x, wq = blockIdx.y, bz = blockIdx.z;
    const int g = bz & 1;
    const int wt = wq * 4 + wave;
    if (wt >= 15) return;

    const short* Ah = Wrh + (long)g * 30720 + ((long)(wt * 4) * 64 + lane) * 8;
    const short* Al = Wrl + (long)g * 30720 + ((long)(wt * 4) * 64 + lane) * 8;
    short8 ahi[4], alo[4];
#pragma unroll
    for (int kc = 0; kc < 4; ++kc) {
        ahi[kc] = *(const short8*)(Ah + kc * 512);
        alo[kc] = *(const short8*)(Al + kc * 512);
    }
    float bb[4];
#pragma unroll
    for (int r = 0; r < 4; ++r) {
        int w = wt * 16 + quad * 4 + r;
        bb[r] = (w < 225) ? brel[g * 225 + w] : 0.f;
    }

    float* relh = rel + (long)bz * 230400;
#pragma unroll
    for (int mtl = 0; mtl < 4; ++mtl) {
        const int mt16 = mb * 4 + mtl;
        const long mrow = (((long)bz << 10) + mt16 * 16 + n16) * 128;
        floatx4 acc = {0.f, 0.f, 0.f, 0.f};
#pragma unroll
        for (int kc = 0; kc < 4; ++kc) {
            long bo = mrow + kc * 32 + quad * 8;
            short8 bh = *(const short8*)(qhi + bo);
            short8 bl = *(const short8*)(qlo + bo);
            acc = __builtin_amdgcn_mfma_f32_16x16x32_bf16(ahi[kc], bh, acc, 0, 0, 0);
            acc = __builtin_amdgcn_mfma_f32_16x16x32_bf16(ahi[kc], bl, acc, 0, 0, 0);
            acc = __builtin_amdgcn_mfma_f32_16x16x32_bf16(alo[kc], bh, acc, 0, 0, 0);
        }
#pragma unroll
        for (int r = 0; r < 4; ++r) {
            int w = wt * 16 + quad * 4 + r;
            if (w < 225)
                relh[((long)w << 10) + mt16 * 16 + n16] = acc[r] + bb[r];
        }
    }
}

// ---------------------------------------------------------------------------
// aggconv: agg fp32 [n][256 c][1024 m] -> B-frag hi/lo
// ---------------------------------------------------------------------------
__global__ __launch_bounds__(256)
void aggconv_kernel(const float* __restrict__ agg,
                    short* __restrict__ Ahi, short* __restrict__ Alo)
{
    __shared__ float st[64 * 33];
    const int tid = threadIdx.x;
    const int mb = blockIdx.x, kc = blockIdx.y, nz = blockIdx.z;
    const float* X = agg + ((long)nz << 18);
#pragma unroll
    for (int it = 0; it < 8; ++it) {
        int e = tid + it * 256;
        int cc = e >> 6, mm = e & 63;
        st[mm * 33 + cc] = X[((long)(kc * 32 + cc) << 10) + mb * 64 + mm];
    }
    __syncthreads();
    const int lane = tid & 63, mtl = tid >> 6;
    const int n16 = lane & 15, quad = lane >> 4;
    const int m = mtl * 16 + n16;
    short h[8], l[8];
#pragma unroll
    for (int j = 0; j < 8; ++j) {
        float f = st[m * 33 + quad * 8 + j];
        short hb = f2bf(f);
        h[j] = hb;
        l[j] = f2bf(f - bf2f(hb));
    }
    int mt16 = mb * 4 + mtl;
    long off = (long)nz * 262144 + (((long)(mt16 * 8 + kc) * 64) + lane) * 8;
    *(short8*)(Ahi + off) = *(short8*)&h[0];
    *(short8*)(Alo + off) = *(short8*)&l[0];
}

// ---------------------------------------------------------------------------
// mfma_fc: out[m][n][d] = Wfc·agg + bfc, interleaved store via LDS transpose.
// ---------------------------------------------------------------------------
__global__ __launch_bounds__(256)
void mfma_fc(const short* __restrict__ Ahi, const short* __restrict__ Alo,
             const short* __restrict__ Whi, const short* __restrict__ Wlo,
             const float* __restrict__ bfc, float* __restrict__ out)
{
    __shared__ float tile[64 * 68];
    const int tid = threadIdx.x;
    const int wave = tid >> 6, lane = tid & 63;
    const int n16 = lane & 15, quad = lane >> 4;
    const int mb = blockIdx.x, db = blockIdx.y, nz = blockIdx.z;
    const int dt = db * 4 + wave;

    const short* Ah = Whi + (long)3 * 65536 + ((long)(dt * 8) * 64 + lane) * 8;
    const short* Al = Wlo + (long)3 * 65536 + ((long)(dt * 8) * 64 + lane) * 8;
    short8 ahi[8], alo[8];
#pragma unroll
    for (int kc = 0; kc < 8; ++kc) {
        ahi[kc] = *(const short8*)(Ah + kc * 512);
        alo[kc] = *(const short8*)(Al + kc * 512);
    }
    const short* Bh = Ahi + (long)nz * 262144;
    const short* Bl = Alo + (long)nz * 262144;

    float4 bv4 = *(const float4*)&bfc[dt * 16 + quad * 4];
    float bb[4] = {bv4.x, bv4.y, bv4.z, bv4.w};

#pragma unroll
    for (int mtl = 0; mtl < 4; ++mtl) {
        const int mt16 = mb * 4 + mtl;
        floatx4 acc = {0.f, 0.f, 0.f, 0.f};
#pragma unroll
        for (int kc = 0; kc < 8; ++kc) {
            long bo = ((long)(mt16 * 8 + kc) * 64 + lane) * 8;
            short8 bh = *(const short8*)(Bh + bo);
            short8 bl = *(const short8*)(Bl + bo);
            acc = __builtin_amdgcn_mfma_f32_16x16x32_bf16(ahi[kc], bh, acc, 0, 0, 0);
            acc = __builtin_amdgcn_mfma_f32_16x16x32_bf16(ahi[kc], bl, acc, 0, 0, 0);
            acc = __builtin_amdgcn_mfma_f32_16x16x32_bf16(alo[kc], bh, acc, 0, 0, 0);
        }
        const int ml = mtl * 16 + n16;
        const int dl = wave * 16 + quad * 4;
#pragma unroll
        for (int r = 0; r < 4; ++r)
            tile[ml * 68 + dl + r] = acc[r] + bb[r];
    }
    __syncthreads();
#pragma unroll
    for (int it = 0; it < 16; ++it) {
        int e = tid + it * 256;
        int dd = e & 63, mm = e >> 6;
        out[(long)(mb * 64 + mm) * 1024 + nz * 256 + db * 64 + dd] = tile[mm * 68 + dd];
    }
}

// ---------------------------------------------------------------------------
// scores via MFMA band-GEMM + softmax (unchanged)
// ---------------------------------------------------------------------------
__global__ __launch_bounds__(256)
void scores_mfma(const short* __restrict__ qhi, const short* __restrict__ qlo,
                 const short* __restrict__ khi, const short* __restrict__ klo,
                 float* __restrict__ relattn)
{
    __shared__ float qk[16 * 241];
    __shared__ float invl[16];

    const int tid = threadIdx.x;
    const int wave = tid >> 6, lane = tid & 63;
    const int y  = blockIdx.x >> 1;
    const int xt = blockIdx.x & 1;
    const int bz = blockIdx.y;
    const int x0 = xt * 16;
    float* relh = relattn + (long)bz * 230400;

    for (int e = tid; e < 16 * 241; e += 256) qk[e] = -1e8f;

    const int n16 = lane & 15, quad = lane >> 4;
    const long qbase = (((long)bz << 10) + y * 32 + x0 + n16) * 128 + quad * 8;
    short8 a_hi[4], a_lo[4];
#pragma unroll
    for (int ch = 0; ch < 4; ++ch) {
        a_hi[ch] = *(const short8*)(qhi + qbase + ch * 32);
        a_lo[ch] = *(const short8*)(qlo + qbase + ch * 32);
    }
    __syncthreads();

    for (int dy = wave; dy < 15; dy += 4) {
        const int ky = y + dy - 7;
        if (ky < 0 || ky > 31) continue;
#pragma unroll
        for (int kxt = 0; kxt < 2; ++kxt) {
            const int kxg = x0 - 8 + kxt * 16 + n16;
            const long kb = (((long)bz << 10) + ky * 32 + kxg) * 128 + quad * 8;
            floatx4 acc = {0.f, 0.f, 0.f, 0.f};
#pragma unroll
            for (int ch = 0; ch < 4; ++ch) {
                short8 b_hi = *(const short8*)(khi + kb + ch * 32);
                short8 b_lo = *(const short8*)(klo + kb + ch * 32);
                acc = __builtin_amdgcn_mfma_f32_16x16x32_bf16(a_hi[ch], b_hi, acc, 0, 0, 0);
                acc = __builtin_amdgcn_mfma_f32_16x16x32_bf16(a_hi[ch], b_lo, acc, 0, 0, 0);
                acc = __builtin_amdgcn_mfma_f32_16x16x32_bf16(a_lo[ch], b_hi, acc, 0, 0, 0);
            }
            if (kxg >= 0 && kxg < 32) {
#pragma unroll
                for (int r = 0; r < 4; ++r) {
                    int m = quad * 4 + r;
                    int dx = kxg - (x0 + m) + 7;
                    if (dx >= 0 && dx < 15)
                        qk[m * 241 + dy * 16 + dx] = acc[r];
                }
            }
        }
    }
    __syncthreads();

    for (int e = tid; e < 3600; e += 256) {
        int px = e & 15, w = e >> 4;
        int dy2 = w / 15, dx2 = w - dy2 * 15;
        qk[px * 241 + dy2 * 16 + dx2] +=
            relh[((long)w << 10) + y * 32 + x0 + px];
    }
    __syncthreads();

    {
        int px = tid >> 4, s = tid & 15;
        float mx = -3.0e38f;
        for (int w = s; w < 240; w += 16) mx = fmaxf(mx, qk[px * 241 + w]);
#pragma unroll
        for (int msk = 8; msk; msk >>= 1) mx = fmaxf(mx, __shfl_xor(mx, msk));
        float sum = 0.f;
        for (int w = s; w < 240; w += 16) {
            float p = __expf(qk[px * 241 + w] - mx);
            qk[px * 241 + w] = p;
            sum += p;
        }
#pragma unroll
        for (int msk = 8; msk; msk >>= 1) sum += __shfl_xor(sum, msk);
        if (s == 0) invl[px] = 1.0f / sum;
    }
    __syncthreads();

    for (int e = tid; e < 3600; e += 256) {
        int px = e & 15, w = e >> 4;
        int dy2 = w / 15, dx2 = w - dy2 * 15;
        relh[((long)w << 10) + y * 32 + x0 + px] =
            qk[px * 241 + dy2 * 16 + dx2] * invl[px];
    }
}

// ---------------------------------------------------------------------------
// PV v4 (unchanged): padded V, register window, dy-half split, atomic agg.
// ---------------------------------------------------------------------------
__global__ __launch_bounds__(256)
void pv_kernel(const float* __restrict__ vpad, const float* __restrict__ attn,
               const float* __restrict__ Vbias, float* __restrict__ agg)
{
    __shared__ __align__(16) float pa[120 * 32];
    const int tid = threadIdx.x;
    const int y   = blockIdx.x;
    const int chh = blockIdx.y & 1;
    const int dyh = blockIdx.y >> 1;
    const int bz  = blockIdx.z;
    const int n = bz >> 1, g = bz & 1;

    const int dy0 = dyh * 8;
    const int ndy = dyh ? 7 : 8;
    const int w0  = dy0 * 15;
    const int nw  = ndy * 15;

    const float* ab = attn + (long)bz * 230400 + ((long)w0 << 10) + y * 32;
    for (int e = tid; e < nw * 8; e += 256) {
        int w = e >> 3, x4 = (e & 7) * 4;
        *(float4*)&pa[w * 32 + x4] = *(const float4*)&ab[((long)w << 10) + x4];
    }
    __syncthreads();

    const int chg = tid >> 3;
    const int xq  = tid & 7;
    const int c0  = chh * 64 + chg * 2;
    const int x0  = xq * 4;
    const float* v0 = vpad + (long)bz * 196608 + (long)c0 * 1536;
    const float* v1 = v0 + 1536;
    const float* b0 = Vbias + (g * 128 + c0) * 225 + w0;
    const float* b1 = b0 + 225;

    float acc0[4] = {0.f, 0.f, 0.f, 0.f};
    float acc1[4] = {0.f, 0.f, 0.f, 0.f};

    for (int d = 0; d < ndy; ++d) {
        int hy = y + dy0 + d - 7;
        if (hy < 0 || hy > 31) continue;
        const float4* r0 = (const float4*)(v0 + hy * 48 + x0);
        const float4* r1 = (const float4*)(v1 + hy * 48 + x0);
        float wa[20], wb[20];
#pragma unroll
        for (int t = 0; t < 5; ++t) {
            float4 a = r0[t], b = r1[t];
            wa[4*t+0] = a.x; wa[4*t+1] = a.y; wa[4*t+2] = a.z; wa[4*t+3] = a.w;
            wb[4*t+0] = b.x; wb[4*t+1] = b.y; wb[4*t+2] = b.z; wb[4*t+3] = b.w;
        }
        const float* par = &pa[d * 15 * 32 + x0];
        const float* vb0 = b0 + d * 15;
        const float* vb1 = b1 + d * 15;
#pragma unroll
        for (int dx = 0; dx < 15; ++dx) {
            float4 p4 = *(const float4*)&par[dx * 32];
            float ba = vb0[dx], bb = vb1[dx];
            acc0[0] += p4.x * (wa[1 + dx] + ba);
            acc0[1] += p4.y * (wa[2 + dx] + ba);
            acc0[2] += p4.z * (wa[3 + dx] + ba);
            acc0[3] += p4.w * (wa[4 + dx] + ba);
            acc1[0] += p4.x * (wb[1 + dx] + bb);
            acc1[1] += p4.y * (wb[2 + dx] + bb);
            acc1[2] += p4.z * (wb[3 + dx] + bb);
            acc1[3] += p4.w * (wb[4 + dx] + bb);
        }
    }

    float* ag = agg + ((long)n << 18) + ((long)(g * 128 + c0) << 10) + y * 32 + x0;
#pragma unroll
    for (int i = 0; i < 4; ++i) atomicAdd(&ag[i], acc0[i]);
#pragma unroll
    for (int i = 0; i < 4; ++i) atomicAdd(&ag[1024 + i], acc1[i]);
}

// ---------------------------------------------------------------------------
// ws floats: vpad@2097152(1572864) agg@3670016(1048576) rel@4718592(1843200)
//   qhi@6561792 qlo@7086080 khi@7610368 klo@8134656 (524288 fl each as shorts)
//   Xhi@8658944(1572864) Xlo@10231808 Whi@11804672(131072) Wlo@11935744
//   AGhi@12066816(524288) AGlo@12591104 Wrh@13115392(30720) Wrl@13146112
//   -> end 13176832 floats (~52.7 MB)
// ---------------------------------------------------------------------------
extern "C" void kernel_launch(void* const* d_in, const int* in_sizes, int n_in,
                              void* d_out, int out_size, void* d_ws, size_t ws_size,
                              hipStream_t stream)
{
    const float* q    = (const float*)d_in[0];
    const float* k    = (const float*)d_in[1];
    const float* v    = (const float*)d_in[2];
    const float* Wq   = (const float*)d_in[3];
    const float* bq   = (const float*)d_in[4];
    const float* Wk   = (const float*)d_in[5];
    const float* bk   = (const float*)d_in[6];
    const float* Wv   = (const float*)d_in[7];
    const float* bv   = (const float*)d_in[8];
    const float* Wrel = (const float*)d_in[9];
    const float* brel = (const float*)d_in[10];
    const float* Vb   = (const float*)d_in[11];
    const float* Wfc  = (const float*)d_in[12];
    const float* bfc  = (const float*)d_in[13];
    float* out = (float*)d_out;

    float* ws   = (float*)d_ws;
    float* vpad = ws + 2097152;
    float* agg  = ws + 3670016;
    float* rel  = ws + 4718592;
    short* qhi  = (short*)(ws + 6561792);
    short* qlo  = (short*)(ws + 7086080);
    short* khi  = (short*)(ws + 7610368);
    short* klo  = (short*)(ws + 8134656);
    short* Xhi  = (short*)(ws + 8658944);
    short* Xlo  = (short*)(ws + 10231808);
    short* Whi  = (short*)(ws + 11804672);
    short* Wlo  = (short*)(ws + 11935744);
    short* AGhi = (short*)(ws + 12066816);
    short* AGlo = (short*)(ws + 12591104);
    short* Wrh  = (short*)(ws + 13115392);
    short* Wrl  = (short*)(ws + 13146112);

    dim3 blk(256);

    // single memset: vpad (pad zeros) + agg (pv atomic target), contiguous
    hipMemsetAsync(vpad, 0, (size_t)(1572864 + 1048576) * 4, stream);

    // fragment conversion: inputs (z 0..11), weights (z 12..15), Wrel (16..17)
    conv_kernel<<<dim3(16, 8, 18), blk, 0, stream>>>(q, k, v, Wq, Wk, Wv, Wfc,
                                                     Wrel, Xhi, Xlo, Whi, Wlo,
                                                     Wrh, Wrl);

    // QKV projections via MFMA -> qhi/qlo, khi/klo (x-major), vpad: 768 blocks
    mfma_proj<<<dim3(16, 4, 12), blk, 0, stream>>>(Xhi, Xlo, Whi, Wlo,
                                                   bq, bk, bv,
                                                   qhi, qlo, khi, klo, vpad);

    // rel logits via MFMA: 512 blocks
    rel_mfma<<<dim3(16, 4, 8), blk, 0, stream>>>(qhi, qlo, Wrh, Wrl, brel, rel);

    // scores via MFMA + softmax -> attn (in place over rel): 512 blocks
    scores_mfma<<<dim3(64, 8), blk, 0, stream>>>(qhi, qlo, khi, klo, rel);

    // PV gather + V_bias fold -> agg (atomic): 1024 blocks
    pv_kernel<<<dim3(32, 4, 8), blk, 0, stream>>>(vpad, rel, Vb, agg);

    // agg -> fragment layout: 512 blocks
    aggconv_kernel<<<dim3(16, 8, 4), blk, 0, stream>>>(agg, AGhi, AGlo);

    // FC via MFMA, interleaved [m][n][c] store: 256 blocks
    mfma_fc<<<dim3(16, 4, 4), blk, 0, stream>>>(AGhi, AGlo, Whi, Wlo, bfc, out);
}

// Round 12
// 173.954 us; speedup vs baseline: 1.3721x; 1.1259x over previous
//
#include <hip/hip_runtime.h>
#include <math.h>

// N=4, C=256, H=W=32, NH=2, HD=128, MAX_DIS=7, WS=15, WW=225, T=sqrt(128)
// out: [hw=1024][n=4][c=256] fp32

typedef __attribute__((ext_vector_type(8))) short short8;
typedef __attribute__((ext_vector_type(4))) float floatx4;

__device__ __forceinline__ short f2bf(float f) {
    unsigned u = __float_as_uint(f);
    unsigned r = (u + 0x7fffu + ((u >> 16) & 1u)) >> 16;
    return (short)r;
}
__device__ __forceinline__ float bf2f(short s) {
    return __uint_as_float(((unsigned)(unsigned short)s) << 16);
}

// ---------------------------------------------------------------------------
// conv_kernel: build bf16 hi/lo MFMA fragment layouts.
// z 0..11 : inputs q/k/v  -> B-frags Xhi/Xlo
// z 12..15: weights Wq,Wk,Wv,Wfc -> A-frags Whi/Wlo
// z 16..17: Wrel per head -> A-frags Wrh/Wrl (15 w-tiles, zero-padded)
// ---------------------------------------------------------------------------
__global__ __launch_bounds__(256)
void conv_kernel(const float* __restrict__ q, const float* __restrict__ k,
                 const float* __restrict__ v,
                 const float* __restrict__ Wq, const float* __restrict__ Wk,
                 const float* __restrict__ Wv, const float* __restrict__ Wfc,
                 const float* __restrict__ Wrel,
                 short* __restrict__ Xhi, short* __restrict__ Xlo,
                 short* __restrict__ Whi, short* __restrict__ Wlo,
                 short* __restrict__ Wrh, short* __restrict__ Wrl)
{
    const int tid = threadIdx.x;
    const int z = blockIdx.z;
    const int lane = tid & 63;
    const int n16 = lane & 15, quad = lane >> 4;

    if (z < 12) {
        __shared__ float st[64 * 33];
        const int sel = z >> 2, batch = z & 3;
        const float* X = (sel == 0 ? q : sel == 1 ? k : v) + ((long)batch << 18);
        const int mb = blockIdx.x, kc = blockIdx.y;
#pragma unroll
        for (int it = 0; it < 8; ++it) {
            int e = tid + it * 256;
            int cc = e >> 6, mm = e & 63;
            st[mm * 33 + cc] = X[((long)(kc * 32 + cc) << 10) + mb * 64 + mm];
        }
        __syncthreads();
        const int mtl = tid >> 6;
        const int m = mtl * 16 + n16;
        short h[8], l[8];
#pragma unroll
        for (int j = 0; j < 8; ++j) {
            float f = st[m * 33 + quad * 8 + j];
            short hb = f2bf(f);
            h[j] = hb;
            l[j] = f2bf(f - bf2f(hb));
        }
        int mt16 = mb * 4 + mtl;
        long off = (long)z * 262144 + (((long)(mt16 * 8 + kc) * 64) + lane) * 8;
        *(short8*)(Xhi + off) = *(short8*)&h[0];
        *(short8*)(Xlo + off) = *(short8*)&l[0];
    } else if (z < 16) {
        if (tid >= 64) return;
        const int w = z - 12;
        const float* W = (w == 0 ? Wq : w == 1 ? Wk : w == 2 ? Wv : Wfc);
        const int dt = blockIdx.x, kc = blockIdx.y;
        const int d = dt * 16 + n16, cb = kc * 32 + quad * 8;
        float4 w0 = *(const float4*)&W[d * 256 + cb];
        float4 w1 = *(const float4*)&W[d * 256 + cb + 4];
        float f[8] = {w0.x, w0.y, w0.z, w0.w, w1.x, w1.y, w1.z, w1.w};
        short h[8], l[8];
#pragma unroll
        for (int j = 0; j < 8; ++j) {
            short hb = f2bf(f[j]);
            h[j] = hb;
            l[j] = f2bf(f[j] - bf2f(hb));
        }
        long off = (long)w * 65536 + (((long)(dt * 8 + kc) * 64) + lane) * 8;
        *(short8*)(Whi + off) = *(short8*)&h[0];
        *(short8*)(Wlo + off) = *(short8*)&l[0];
    } else {
        if (tid >= 64) return;
        const int g = z - 16;
        const int wt = blockIdx.x, kc = blockIdx.y;
        if (wt >= 15 || kc >= 4) return;
        const int w = wt * 16 + n16;         // 0..239, valid < 225
        const int cb = kc * 32 + quad * 8;
        float f[8] = {0.f, 0.f, 0.f, 0.f, 0.f, 0.f, 0.f, 0.f};
        if (w < 225) {
            float4 w0 = *(const float4*)&Wrel[(long)(g * 225 + w) * 128 + cb];
            float4 w1 = *(const float4*)&Wrel[(long)(g * 225 + w) * 128 + cb + 4];
            f[0] = w0.x; f[1] = w0.y; f[2] = w0.z; f[3] = w0.w;
            f[4] = w1.x; f[5] = w1.y; f[6] = w1.z; f[7] = w1.w;
        }
        short h[8], l[8];
#pragma unroll
        for (int j = 0; j < 8; ++j) {
            short hb = f2bf(f[j]);
            h[j] = hb;
            l[j] = f2bf(f[j] - bf2f(hb));
        }
        long off = (long)g * 30720 + (((long)(wt * 4 + kc) * 64) + lane) * 8;
        *(short8*)(Wrh + off) = *(short8*)&h[0];
        *(short8*)(Wrl + off) = *(short8*)&l[0];
    }
}

// ---------------------------------------------------------------------------
// mfma_proj: Y = W·X for q/k/v with hi/lo split (3 MFMAs per k-chunk).
// grid (mb 16, db 4, z 12). Epilogues:
//   sel 0/1: LDS transpose -> x-major bf16 hi/lo (q unscaled, k * 1/T)
//   sel 2  : fp32 -> padded vpad layout
// ---------------------------------------------------------------------------
__global__ __launch_bounds__(256)
void mfma_proj(const short* __restrict__ Xhi, const short* __restrict__ Xlo,
               const short* __restrict__ Whi, const short* __restrict__ Wlo,
               const float* __restrict__ bq, const float* __restrict__ bk,
               const float* __restrict__ bv,
               short* __restrict__ qhi, short* __restrict__ qlo,
               short* __restrict__ khi, short* __restrict__ klo,
               float* __restrict__ vpad)
{
    __shared__ float tile[64 * 65];
    const int tid = threadIdx.x;
    const int wave = tid >> 6, lane = tid & 63;
    const int n16 = lane & 15, quad = lane >> 4;
    const int mb = blockIdx.x, db = blockIdx.y, z = blockIdx.z;
    const int sel = z >> 2, batch = z & 3;
    const int dt = db * 4 + wave;

    const short* Ah = Whi + (long)sel * 65536 + ((long)(dt * 8) * 64 + lane) * 8;
    const short* Al = Wlo + (long)sel * 65536 + ((long)(dt * 8) * 64 + lane) * 8;
    short8 ahi[8], alo[8];
#pragma unroll
    for (int kc = 0; kc < 8; ++kc) {
        ahi[kc] = *(const short8*)(Ah + kc * 512);
        alo[kc] = *(const short8*)(Al + kc * 512);
    }
    const short* Bh = Xhi + (long)z * 262144;
    const short* Bl = Xlo + (long)z * 262144;

    const float* bias = (sel == 0 ? bq : sel == 1 ? bk : bv);
    float4 bv4 = *(const float4*)&bias[dt * 16 + quad * 4];
    float bb[4] = {bv4.x, bv4.y, bv4.z, bv4.w};

    if (sel == 2) {
#pragma unroll
        for (int mtl = 0; mtl < 4; ++mtl) {
            const int mt16 = mb * 4 + mtl;
            floatx4 acc = {0.f, 0.f, 0.f, 0.f};
#pragma unroll
            for (int kc = 0; kc < 8; ++kc) {
                long bo = ((long)(mt16 * 8 + kc) * 64 + lane) * 8;
                short8 bh = *(const short8*)(Bh + bo);
                short8 bl = *(const short8*)(Bl + bo);
                acc = __builtin_amdgcn_mfma_f32_16x16x32_bf16(ahi[kc], bh, acc, 0, 0, 0);
                acc = __builtin_amdgcn_mfma_f32_16x16x32_bf16(ahi[kc], bl, acc, 0, 0, 0);
                acc = __builtin_amdgcn_mfma_f32_16x16x32_bf16(alo[kc], bh, acc, 0, 0, 0);
            }
            const int m = mt16 * 16 + n16;
            float* Y = vpad + (long)batch * 393216;
            const int row = m >> 5, col = (m & 31) + 8;
#pragma unroll
            for (int r = 0; r < 4; ++r)
                Y[(long)(dt * 16 + quad * 4 + r) * 1536 + row * 48 + col] = acc[r] + bb[r];
        }
        return;
    }

#pragma unroll
    for (int mtl = 0; mtl < 4; ++mtl) {
        const int mt16 = mb * 4 + mtl;
        floatx4 acc = {0.f, 0.f, 0.f, 0.f};
#pragma unroll
        for (int kc = 0; kc < 8; ++kc) {
            long bo = ((long)(mt16 * 8 + kc) * 64 + lane) * 8;
            short8 bh = *(const short8*)(Bh + bo);
            short8 bl = *(const short8*)(Bl + bo);
            acc = __builtin_amdgcn_mfma_f32_16x16x32_bf16(ahi[kc], bh, acc, 0, 0, 0);
            acc = __builtin_amdgcn_mfma_f32_16x16x32_bf16(ahi[kc], bl, acc, 0, 0, 0);
            acc = __builtin_amdgcn_mfma_f32_16x16x32_bf16(alo[kc], bh, acc, 0, 0, 0);
        }
        const int ml = mtl * 16 + n16;
        const int cl = wave * 16 + quad * 4;
#pragma unroll
        for (int r = 0; r < 4; ++r)
            tile[ml * 65 + cl + r] = acc[r] + bb[r];
    }
    __syncthreads();

    const float scale = (sel == 1) ? 0.08838834764831845f : 1.0f;
    const int m_l = tid >> 2, c16 = (tid & 3) * 16;
    const int m = mb * 64 + m_l;
    const int cglob = db * 64 + c16;
    const int g = cglob >> 7, ch = cglob & 127;
    const long base = (((long)(batch * 2 + g) << 10) + m) * 128 + ch;
    short h[16], l[16];
#pragma unroll
    for (int j = 0; j < 16; ++j) {
        float f = tile[m_l * 65 + c16 + j] * scale;
        short hb = f2bf(f);
        h[j] = hb;
        l[j] = f2bf(f - bf2f(hb));
    }
    short* oh = sel ? khi : qhi;
    short* ol = sel ? klo : qlo;
    *(short8*)(oh + base)     = *(short8*)&h[0];
    *(short8*)(oh + base + 8) = *(short8*)&h[8];
    *(short8*)(ol + base)     = *(short8*)&l[0];
    *(short8*)(ol + base + 8) = *(short8*)&l[8];
}

// ---------------------------------------------------------------------------
// scores_mfma v2: rel fused. block = (y, x-tile 16px, bz), grid (64,8).
// Phase R: rel = Wrel·q via MFMA (q frag doubles as B operand!) -> qk LDS
// Phase M: mask invalid/pad slots to -1e8
// Phase B: band QK^T via MFMA, qk[slot] += S (exclusive owner)
// then softmax + normalized attn writeback.
// ---------------------------------------------------------------------------
__global__ __launch_bounds__(256)
void scores_mfma(const short* __restrict__ qhi, const short* __restrict__ qlo,
                 const short* __restrict__ khi, const short* __restrict__ klo,
                 const short* __restrict__ Wrh, const short* __restrict__ Wrl,
                 const float* __restrict__ brel, float* __restrict__ attn)
{
    __shared__ float qk[16 * 241];
    __shared__ float invl[16];

    const int tid = threadIdx.x;
    const int wave = tid >> 6, lane = tid & 63;
    const int y  = blockIdx.x >> 1;
    const int xt = blockIdx.x & 1;
    const int bz = blockIdx.y;
    const int g = bz & 1;
    const int x0 = xt * 16;
    float* relh = attn + (long)bz * 230400;

    const int n16 = lane & 15, quad = lane >> 4;
    const long qbase = (((long)bz << 10) + y * 32 + x0 + n16) * 128 + quad * 8;
    short8 a_hi[4], a_lo[4];
#pragma unroll
    for (int ch = 0; ch < 4; ++ch) {
        a_hi[ch] = *(const short8*)(qhi + qbase + ch * 32);
        a_lo[ch] = *(const short8*)(qlo + qbase + ch * 32);
    }

    // ---- phase R: rel logits (A = Wrel frags, B = q frags = a_hi/a_lo) ----
    for (int wt = wave; wt < 15; wt += 4) {
        const short* Ah = Wrh + (long)g * 30720 + ((long)(wt * 4) * 64 + lane) * 8;
        const short* Al = Wrl + (long)g * 30720 + ((long)(wt * 4) * 64 + lane) * 8;
        floatx4 racc = {0.f, 0.f, 0.f, 0.f};
#pragma unroll
        for (int kc = 0; kc < 4; ++kc) {
            short8 whh = *(const short8*)(Ah + kc * 512);
            short8 wll = *(const short8*)(Al + kc * 512);
            racc = __builtin_amdgcn_mfma_f32_16x16x32_bf16(whh, a_hi[kc], racc, 0, 0, 0);
            racc = __builtin_amdgcn_mfma_f32_16x16x32_bf16(whh, a_lo[kc], racc, 0, 0, 0);
            racc = __builtin_amdgcn_mfma_f32_16x16x32_bf16(wll, a_hi[kc], racc, 0, 0, 0);
        }
#pragma unroll
        for (int r = 0; r < 4; ++r) {
            int w = wt * 16 + quad * 4 + r;
            if (w < 225) {
                int dy = w / 15, dx = w - dy * 15;
                qk[n16 * 241 + dy * 16 + dx] = racc[r] + brel[g * 225 + w];
            }
        }
    }
    __syncthreads();

    // ---- phase M: mask invalid neighbors and pad slots ----
    for (int e = tid; e < 16 * 241; e += 256) {
        int px = e / 241, idx = e - px * 241;
        int dy = idx >> 4, dx = idx & 15;
        int hy = y + dy - 7, hx = x0 + px + dx - 7;
        bool valid = (dx < 15) && (dy < 15) &&
                     (hy >= 0) && (hy < 32) && (hx >= 0) && (hx < 32);
        if (!valid) qk[e] = -1e8f;
    }
    __syncthreads();

    // ---- phase B: band QK^T, accumulate into qk ----
    for (int dy = wave; dy < 15; dy += 4) {
        const int ky = y + dy - 7;
        if (ky < 0 || ky > 31) continue;
#pragma unroll
        for (int kxt = 0; kxt < 2; ++kxt) {
            const int kxg = x0 - 8 + kxt * 16 + n16;
            const long kb = (((long)bz << 10) + ky * 32 + kxg) * 128 + quad * 8;
            floatx4 acc = {0.f, 0.f, 0.f, 0.f};
#pragma unroll
            for (int ch = 0; ch < 4; ++ch) {
                short8 b_hi = *(const short8*)(khi + kb + ch * 32);
                short8 b_lo = *(const short8*)(klo + kb + ch * 32);
                acc = __builtin_amdgcn_mfma_f32_16x16x32_bf16(a_hi[ch], b_hi, acc, 0, 0, 0);
                acc = __builtin_amdgcn_mfma_f32_16x16x32_bf16(a_hi[ch], b_lo, acc, 0, 0, 0);
                acc = __builtin_amdgcn_mfma_f32_16x16x32_bf16(a_lo[ch], b_hi, acc, 0, 0, 0);
            }
            if (kxg >= 0 && kxg < 32) {
#pragma unroll
                for (int r = 0; r < 4; ++r) {
                    int m = quad * 4 + r;
                    int dx = kxg - (x0 + m) + 7;
                    if (dx >= 0 && dx < 15) {
                        int s = m * 241 + dy * 16 + dx;
                        qk[s] = qk[s] + acc[r];
                    }
                }
            }
        }
    }
    __syncthreads();

    // ---- softmax over 240 slots: 16 threads per px ----
    {
        int px = tid >> 4, s = tid & 15;
        float mx = -3.0e38f;
        for (int w = s; w < 240; w += 16) mx = fmaxf(mx, qk[px * 241 + w]);
#pragma unroll
        for (int msk = 8; msk; msk >>= 1) mx = fmaxf(mx, __shfl_xor(mx, msk));
        float sum = 0.f;
        for (int w = s; w < 240; w += 16) {
            float p = __expf(qk[px * 241 + w] - mx);
            qk[px * 241 + w] = p;
            sum += p;
        }
#pragma unroll
        for (int msk = 8; msk; msk >>= 1) sum += __shfl_xor(sum, msk);
        if (s == 0) invl[px] = 1.0f / sum;
    }
    __syncthreads();

    // ---- normalized attention writeback ----
    for (int e = tid; e < 3600; e += 256) {
        int px = e & 15, w = e >> 4;
        int dy2 = w / 15, dx2 = w - dy2 * 15;
        relh[((long)w << 10) + y * 32 + x0 + px] =
            qk[px * 241 + dy2 * 16 + dx2] * invl[px];
    }
}

// ---------------------------------------------------------------------------
// pv v5: full-dy blocks, frag epilogue (aggconv fused).
// grid (y 32, chh 2, bz 8) = 512 blocks; thread = 2 ch x 4 px, 15 dy.
// Epilogue: fp32 tile -> LDS -> bf16 hi/lo B-frags (coalesced short8 stores).
// ---------------------------------------------------------------------------
__global__ __launch_bounds__(256)
void pv_kernel(const float* __restrict__ vpad, const float* __restrict__ attn,
               const float* __restrict__ Vbias,
               short* __restrict__ AGhi, short* __restrict__ AGlo)
{
    __shared__ __align__(16) float pa[225 * 32];   // 28.8 KB, reused as tile
    const int tid = threadIdx.x;
    const int y   = blockIdx.x;
    const int chh = blockIdx.y;
    const int bz  = blockIdx.z;
    const int n = bz >> 1, g = bz & 1;

    const float* ab = attn + (long)bz * 230400 + y * 32;
    for (int e = tid; e < 1800; e += 256) {
        int w = e >> 3, x4 = (e & 7) * 4;
        *(float4*)&pa[w * 32 + x4] = *(const float4*)&ab[((long)w << 10) + x4];
    }
    __syncthreads();

    const int chg = tid >> 3;            // 0..31 -> 2 channels each
    const int xq  = tid & 7;
    const int c0  = chh * 64 + chg * 2;  // channel base within head
    const int x0  = xq * 4;
    const float* v0 = vpad + (long)bz * 196608 + (long)c0 * 1536;
    const float* v1 = v0 + 1536;
    const float* b0 = Vbias + (g * 128 + c0) * 225;
    const float* b1 = b0 + 225;

    float acc0[4] = {0.f, 0.f, 0.f, 0.f};
    float acc1[4] = {0.f, 0.f, 0.f, 0.f};

    for (int dy = 0; dy < 15; ++dy) {
        int hy = y + dy - 7;
        if (hy < 0 || hy > 31) continue;           // p == 0 for this dy
        const float4* r0 = (const float4*)(v0 + hy * 48 + x0);
        const float4* r1 = (const float4*)(v1 + hy * 48 + x0);
        float wa[20], wb[20];
#pragma unroll
        for (int t = 0; t < 5; ++t) {
            float4 a = r0[t], b = r1[t];
            wa[4*t+0] = a.x; wa[4*t+1] = a.y; wa[4*t+2] = a.z; wa[4*t+3] = a.w;
            wb[4*t+0] = b.x; wb[4*t+1] = b.y; wb[4*t+2] = b.z; wb[4*t+3] = b.w;
        }
        const float* par = &pa[dy * 15 * 32 + x0];
        const float* vb0 = b0 + dy * 15;
        const float* vb1 = b1 + dy * 15;
#pragma unroll
        for (int dx = 0; dx < 15; ++dx) {
            float4 p4 = *(const float4*)&par[dx * 32];
            float ba = vb0[dx], bb = vb1[dx];
            acc0[0] += p4.x * (wa[1 + dx] + ba);
            acc0[1] += p4.y * (wa[2 + dx] + ba);
            acc0[2] += p4.z * (wa[3 + dx] + ba);
            acc0[3] += p4.w * (wa[4 + dx] + ba);
            acc1[0] += p4.x * (wb[1 + dx] + bb);
            acc1[1] += p4.y * (wb[2 + dx] + bb);
            acc1[2] += p4.z * (wb[3 + dx] + bb);
            acc1[3] += p4.w * (wb[4 + dx] + bb);
        }
    }
    __syncthreads();                     // all pa reads done -> reuse as tile

    float* tile = pa;                    // [32 m][65 c]
#pragma unroll
    for (int i = 0; i < 4; ++i) {
        tile[(x0 + i) * 65 + chg * 2 + 0] = acc0[i];
        tile[(x0 + i) * 65 + chg * 2 + 1] = acc1[i];
    }
    __syncthreads();

    // frag conversion: thread -> (mtp, kcp, lane)
    const int lane = tid & 63, sub = tid >> 6;
    const int kcp = sub & 1, mtp = sub >> 1;
    const int n16 = lane & 15, quad = lane >> 4;
    const int m_loc = mtp * 16 + n16;
    const int c_loc = kcp * 32 + quad * 8;
    short h[8], l[8];
#pragma unroll
    for (int j = 0; j < 8; ++j) {
        float f = tile[m_loc * 65 + c_loc + j];
        short hb = f2bf(f);
        h[j] = hb;
        l[j] = f2bf(f - bf2f(hb));
    }
    const int mt16 = y * 2 + mtp;
    const int kc = g * 4 + chh * 2 + kcp;
    long off = (long)n * 262144 + (((long)(mt16 * 8 + kc) * 64) + lane) * 8;
    *(short8*)(AGhi + off) = *(short8*)&h[0];
    *(short8*)(AGlo + off) = *(short8*)&l[0];
}

// ---------------------------------------------------------------------------
// mfma_fc: out[m][n][d] = Wfc·agg + bfc, interleaved store via LDS transpose.
// ---------------------------------------------------------------------------
__global__ __launch_bounds__(256)
void mfma_fc(const short* __restrict__ Ahi, const short* __restrict__ Alo,
             const short* __restrict__ Whi, const short* __restrict__ Wlo,
             const float* __restrict__ bfc, float* __restrict__ out)
{
    __shared__ float tile[64 * 68];
    const int tid = threadIdx.x;
    const int wave = tid >> 6, lane = tid & 63;
    const int n16 = lane & 15, quad = lane >> 4;
    const int mb = blockIdx.x, db = blockIdx.y, nz = blockIdx.z;
    const int dt = db * 4 + wave;

    const short* Ah = Whi + (long)3 * 65536 + ((long)(dt * 8) * 64 + lane) * 8;
    const short* Al = Wlo + (long)3 * 65536 + ((long)(dt * 8) * 64 + lane) * 8;
    short8 ahi[8], alo[8];
#pragma unroll
    for (int kc = 0; kc < 8; ++kc) {
        ahi[kc] = *(const short8*)(Ah + kc * 512);
        alo[kc] = *(const short8*)(Al + kc * 512);
    }
    const short* Bh = Ahi + (long)nz * 262144;
    const short* Bl = Alo + (long)nz * 262144;

    float4 bv4 = *(const float4*)&bfc[dt * 16 + quad * 4];
    float bb[4] = {bv4.x, bv4.y, bv4.z, bv4.w};

#pragma unroll
    for (int mtl = 0; mtl < 4; ++mtl) {
        const int mt16 = mb * 4 + mtl;
        floatx4 acc = {0.f, 0.f, 0.f, 0.f};
#pragma unroll
        for (int kc = 0; kc < 8; ++kc) {
            long bo = ((long)(mt16 * 8 + kc) * 64 + lane) * 8;
            short8 bh = *(const short8*)(Bh + bo);
            short8 bl = *(const short8*)(Bl + bo);
            acc = __builtin_amdgcn_mfma_f32_16x16x32_bf16(ahi[kc], bh, acc, 0, 0, 0);
            acc = __builtin_amdgcn_mfma_f32_16x16x32_bf16(ahi[kc], bl, acc, 0, 0, 0);
            acc = __builtin_amdgcn_mfma_f32_16x16x32_bf16(alo[kc], bh, acc, 0, 0, 0);
        }
        const int ml = mtl * 16 + n16;
        const int dl = wave * 16 + quad * 4;
#pragma unroll
        for (int r = 0; r < 4; ++r)
            tile[ml * 68 + dl + r] = acc[r] + bb[r];
    }
    __syncthreads();
#pragma unroll
    for (int it = 0; it < 16; ++it) {
        int e = tid + it * 256;
        int dd = e & 63, mm = e >> 6;
        out[(long)(mb * 64 + mm) * 1024 + nz * 256 + db * 64 + dd] = tile[mm * 68 + dd];
    }
}

// ---------------------------------------------------------------------------
// ws floats: vpad@2097152(1572864) attn@4718592(1843200)
//   qhi@6561792 qlo@7086080 khi@7610368 klo@8134656 (524288 fl each as shorts)
//   Xhi@8658944(1572864) Xlo@10231808 Whi@11804672(131072) Wlo@11935744
//   AGhi@12066816(524288) AGlo@12591104 Wrh@13115392(30720) Wrl@13146112
// ---------------------------------------------------------------------------
extern "C" void kernel_launch(void* const* d_in, const int* in_sizes, int n_in,
                              void* d_out, int out_size, void* d_ws, size_t ws_size,
                              hipStream_t stream)
{
    const float* q    = (const float*)d_in[0];
    const float* k    = (const float*)d_in[1];
    const float* v    = (const float*)d_in[2];
    const float* Wq   = (const float*)d_in[3];
    const float* bq   = (const float*)d_in[4];
    const float* Wk   = (const float*)d_in[5];
    const float* bk   = (const float*)d_in[6];
    const float* Wv   = (const float*)d_in[7];
    const float* bv   = (const float*)d_in[8];
    const float* Wrel = (const float*)d_in[9];
    const float* brel = (const float*)d_in[10];
    const float* Vb   = (const float*)d_in[11];
    const float* Wfc  = (const float*)d_in[12];
    const float* bfc  = (const float*)d_in[13];
    float* out = (float*)d_out;

    float* ws   = (float*)d_ws;
    float* vpad = ws + 2097152;
    float* attn = ws + 4718592;
    short* qhi  = (short*)(ws + 6561792);
    short* qlo  = (short*)(ws + 7086080);
    short* khi  = (short*)(ws + 7610368);
    short* klo  = (short*)(ws + 8134656);
    short* Xhi  = (short*)(ws + 8658944);
    short* Xlo  = (short*)(ws + 10231808);
    short* Whi  = (short*)(ws + 11804672);
    short* Wlo  = (short*)(ws + 11935744);
    short* AGhi = (short*)(ws + 12066816);
    short* AGlo = (short*)(ws + 12591104);
    short* Wrh  = (short*)(ws + 13115392);
    short* Wrl  = (short*)(ws + 13146112);

    dim3 blk(256);

    // only vpad needs zero padding now
    hipMemsetAsync(vpad, 0, (size_t)1572864 * 4, stream);

    // fragment conversion: inputs (z 0..11), weights (z 12..15), Wrel (16..17)
    conv_kernel<<<dim3(16, 8, 18), blk, 0, stream>>>(q, k, v, Wq, Wk, Wv, Wfc,
                                                     Wrel, Xhi, Xlo, Whi, Wlo,
                                                     Wrh, Wrl);

    // QKV projections via MFMA -> qhi/qlo, khi/klo (x-major), vpad: 768 blocks
    mfma_proj<<<dim3(16, 4, 12), blk, 0, stream>>>(Xhi, Xlo, Whi, Wlo,
                                                   bq, bk, bv,
                                                   qhi, qlo, khi, klo, vpad);

    // scores (rel fused) via MFMA + softmax -> attn: 512 blocks
    scores_mfma<<<dim3(64, 8), blk, 0, stream>>>(qhi, qlo, khi, klo,
                                                 Wrh, Wrl, brel, attn);

    // PV gather + V_bias fold -> AG frags directly: 512 blocks
    pv_kernel<<<dim3(32, 2, 8), blk, 0, stream>>>(vpad, attn, Vb, AGhi, AGlo);

    // FC via MFMA, interleaved [m][n][c] store: 256 blocks
    mfma_fc<<<dim3(16, 4, 4), blk, 0, stream>>>(AGhi, AGlo, Whi, Wlo, bfc, out);
}